// Round 7
// baseline (606.076 us; speedup 1.0000x reference)
//
#include <hip/hip_runtime.h>
#include <stdint.h>
#include <stddef.h>

// ---------------- problem constants ----------------
constexpr int Bb  = 4;
constexpr int Nn  = 2048;
constexpr int Ee  = 1024;    // embed dim
constexpr int KVd = 512;     // kv dim
constexpr int HDd = 128;     // head dim
constexpr int KVH = 4;       // kv heads
constexpr int Tt  = Bb * Nn; // 8192 tokens

typedef _Float16 half8 __attribute__((ext_vector_type(8)));
typedef float    float4_t __attribute__((ext_vector_type(4)));
typedef int      i32x4 __attribute__((ext_vector_type(4)));

// ---------------- workspace layout (bytes) ----------------
constexpr size_t OFF_STATS = 0;                                  // 8 floats
constexpr size_t OFF_SQ  = 256;                                  // 1 MB  int8 sign(w_q-mean)
constexpr size_t OFF_SK  = OFF_SQ  + (size_t)Ee*Ee;              // 512 KB
constexpr size_t OFF_SV  = OFF_SK  + (size_t)KVd*Ee;             // 512 KB
constexpr size_t OFF_SO  = OFF_SV  + (size_t)KVd*Ee;             // 512 KB
constexpr size_t OFF_XQQ = OFF_SO  + (size_t)Ee*KVd;             // 8 MB  int8 quant inputs
constexpr size_t OFF_XQK = OFF_XQQ + (size_t)Tt*Ee;
constexpr size_t OFF_XQV = OFF_XQK + (size_t)Tt*Ee;
constexpr size_t OFF_XSQ = OFF_XQV + (size_t)Tt*Ee;              // per-token dequant scales
constexpr size_t OFF_XSK = OFF_XSQ + (size_t)Tt*4;
constexpr size_t OFF_XSV = OFF_XSK + (size_t)Tt*4;
constexpr size_t OFF_PQ  = OFF_XSV + (size_t)Tt*4;               // 32 MB fp32 q-proj
constexpr size_t OFF_PK  = OFF_PQ  + (size_t)Tt*Ee*4;            // 16 MB
constexpr size_t OFF_PV  = OFF_PK  + (size_t)Tt*KVd*4;           // 16 MB
// aliases (regions dead by the time these are written):
constexpr size_t OFF_PKH = OFF_XQQ;                              // 8 MB f16 K packed (xq_q dead after gemm Q)
constexpr size_t OFF_PVT = OFF_XQK;                              // 8 MB f16 V packed (xq_k dead after gemm KV)
constexpr size_t OFF_AO  = OFF_PK;                               // 16 MB over Pk fp32 (dead after k_pack)
constexpr size_t OFF_OQ  = OFF_XQV;                              // 4 MB over XQV (dead after gemm KV)
constexpr size_t OFF_OS  = OFF_OQ + (size_t)Tt*KVd;              // 32 KB, still inside XQV
constexpr size_t OFF_PART = OFF_PQ;                              // 4 KB partials alias Pq (consumed first)

// ---------------- DPP 16-lane replicated reductions (VALU-only) ----------------
template <int CTRL>
__device__ __forceinline__ float dpp_f(float x) {
  int i = __builtin_bit_cast(int, x);
  i = __builtin_amdgcn_update_dpp(0, i, CTRL, 0xF, 0xF, true);
  return __builtin_bit_cast(float, i);
}
__device__ __forceinline__ float red16_max(float x) {
  x = fmaxf(x, dpp_f<0xB1>(x));    // quad_perm [1,0,3,2]  (xor 1)
  x = fmaxf(x, dpp_f<0x4E>(x));    // quad_perm [2,3,0,1]  (xor 2)
  x = fmaxf(x, dpp_f<0x141>(x));   // row_half_mirror
  x = fmaxf(x, dpp_f<0x140>(x));   // row_mirror
  return x;
}
__device__ __forceinline__ float red16_sum(float x) {
  x += dpp_f<0xB1>(x);
  x += dpp_f<0x4E>(x);
  x += dpp_f<0x141>(x);
  x += dpp_f<0x140>(x);
  return x;
}

// ---------------- weight stats, stage 1 ----------------
constexpr int SB = 64;  // stat blocks per matrix

__global__ __launch_bounds__(256) void weight_stats_part(
    const float* __restrict__ w0, const float* __restrict__ w1,
    const float* __restrict__ w2, const float* __restrict__ w3,
    double* __restrict__ partials)
{
  const float* w; int n;
  switch (blockIdx.y) {
    case 0:  w = w0; n = Ee*Ee;  break;
    case 1:  w = w1; n = KVd*Ee; break;
    case 2:  w = w2; n = KVd*Ee; break;
    default: w = w3; n = Ee*KVd; break;
  }
  const int nv = n >> 2;
  double s = 0.0, sa = 0.0;
  for (int i = blockIdx.x * 256 + threadIdx.x; i < nv; i += SB * 256) {
    float4 v = ((const float4*)w)[i];
    s  += (double)v.x + (double)v.y + (double)v.z + (double)v.w;
    sa += (double)fabsf(v.x) + (double)fabsf(v.y) + (double)fabsf(v.z) + (double)fabsf(v.w);
  }
  __shared__ double r0[256], r1[256];
  r0[threadIdx.x] = s; r1[threadIdx.x] = sa;
  __syncthreads();
  for (int st = 128; st > 0; st >>= 1) {
    if (threadIdx.x < st) { r0[threadIdx.x] += r0[threadIdx.x+st]; r1[threadIdx.x] += r1[threadIdx.x+st]; }
    __syncthreads();
  }
  if (threadIdx.x == 0) {
    size_t o = ((size_t)blockIdx.y * SB + blockIdx.x) * 2;
    partials[o]   = r0[0];
    partials[o+1] = r1[0];
  }
}

__global__ __launch_bounds__(64) void weight_stats_fin(
    const double* __restrict__ partials, float* __restrict__ stats)
{
  int m = threadIdx.x;
  if (m < 4) {
    double s = 0.0, sa = 0.0;
    for (int i = 0; i < SB; i++) {
      s  += partials[((size_t)m * SB + i) * 2];
      sa += partials[((size_t)m * SB + i) * 2 + 1];
    }
    int n = (m == 0) ? Ee*Ee : (m == 3 ? Ee*KVd : KVd*Ee);
    stats[2*m]   = (float)(s  / n);
    stats[2*m+1] = (float)(sa / n);
  }
}

// ---------------- ternary weight signs ----------------
__global__ __launch_bounds__(256) void quant_w(
    const float* __restrict__ w, int8_t* __restrict__ s, int n,
    const float* __restrict__ stats, int idx)
{
  int i = blockIdx.x * 256 + threadIdx.x;
  if (i < n) {
    float d = w[i] - stats[2*idx];
    s[i] = (d > 0.f) ? (int8_t)1 : ((d < 0.f) ? (int8_t)-1 : (int8_t)0);
  }
}

// ---------------- fused rmsnorm + int8 act quant (dim=1024) ----------------
__global__ __launch_bounds__(256) void act_quant_e(
    const float* __restrict__ x, int8_t* __restrict__ q, float* __restrict__ dq)
{
  __shared__ float r0[256], r1[256];
  __shared__ float sb[2];
  const int t = blockIdx.x, tid = threadIdx.x;
  float4 a = ((const float4*)(x + (size_t)t * Ee))[tid];
  float ss = a.x*a.x + a.y*a.y + a.z*a.z + a.w*a.w;
  float mx = fmaxf(fmaxf(fabsf(a.x), fabsf(a.y)), fmaxf(fabsf(a.z), fabsf(a.w)));
  r0[tid] = ss; r1[tid] = mx;
  __syncthreads();
  for (int st = 128; st > 0; st >>= 1) {
    if (tid < st) { r0[tid] += r0[tid+st]; r1[tid] = fmaxf(r1[tid], r1[tid+st]); }
    __syncthreads();
  }
  if (tid == 0) {
    float nrm = sqrtf(r0[0]);
    float rn  = sqrtf((float)Ee) / fmaxf(nrm, 1e-12f);
    float sc  = 127.0f / fmaxf(r1[0] * rn, 1e-5f);
    sb[0] = rn; sb[1] = sc;
    dq[t] = 1.0f / sc;
  }
  __syncthreads();
  const float rn = sb[0], sc = sb[1];
  char4 o;
  o.x = (signed char)fmaxf(fminf(rintf((a.x*rn)*sc), 127.f), -128.f);
  o.y = (signed char)fmaxf(fminf(rintf((a.y*rn)*sc), 127.f), -128.f);
  o.z = (signed char)fmaxf(fminf(rintf((a.z*rn)*sc), 127.f), -128.f);
  o.w = (signed char)fmaxf(fminf(rintf((a.w*rn)*sc), 127.f), -128.f);
  ((char4*)(q + (size_t)t * Ee))[tid] = o;
}

// ---------------- int8 x ternary GEMM via MFMA (exact i32 accumulate) ----------------
// 2-phase pipelined: loads for tile k+1 issued AFTER the barrier, BEFORE the
// MFMA cluster of tile k, so global latency hides under MFMAs (T3 minimal).
__device__ __forceinline__ void gemm_core(
    const int8_t* __restrict__ A, const int8_t* __restrict__ Bm,
    const float* __restrict__ xs, const float* __restrict__ stats, int widx,
    float* __restrict__ C, int Nc, int K, int bx, int by)
{
  __shared__ int8_t As[128 * 80];   // 80-B padded rows
  __shared__ int8_t Bs[128 * 80];
  const int tid = threadIdx.x;
  const int row0 = by * 128, col0 = bx * 128;
  const int lane = tid & 63, wave = tid >> 6;
  const int wr = wave >> 1, wc = wave & 1;
  const int c = lane & 15, quad = lane >> 4;

  i32x4 acc[4][4];
  #pragma unroll
  for (int mt = 0; mt < 4; mt++)
    #pragma unroll
    for (int nt = 0; nt < 4; nt++) acc[mt][nt] = (i32x4){0, 0, 0, 0};

  const int srow = tid >> 2;
  const int schunk = (tid & 3) * 16;
  const int8_t* pa0 = A  + (size_t)(row0 + srow)      * K + schunk;
  const int8_t* pa1 = A  + (size_t)(row0 + 64 + srow) * K + schunk;
  const int8_t* pb0 = Bm + (size_t)(col0 + srow)      * K + schunk;
  const int8_t* pb1 = Bm + (size_t)(col0 + 64 + srow) * K + schunk;

  int4 a0 = *(const int4*)(pa0);
  int4 a1 = *(const int4*)(pa1);
  int4 b0 = *(const int4*)(pb0);
  int4 b1 = *(const int4*)(pb1);

  for (int k0 = 0; k0 < K; k0 += 64) {
    __syncthreads();
    *(int4*)&As[srow * 80 + schunk]        = a0;
    *(int4*)&As[(64 + srow) * 80 + schunk] = a1;
    *(int4*)&Bs[srow * 80 + schunk]        = b0;
    *(int4*)&Bs[(64 + srow) * 80 + schunk] = b1;
    __syncthreads();
    // issue next-tile loads before MFMA cluster (latency hidden by MFMAs)
    const int kn = (k0 + 64 < K) ? k0 + 64 : k0;
    a0 = *(const int4*)(pa0 + kn);
    a1 = *(const int4*)(pa1 + kn);
    b0 = *(const int4*)(pb0 + kn);
    b1 = *(const int4*)(pb1 + kn);
    i32x4 af[4], bf[4];
    #pragma unroll
    for (int mt = 0; mt < 4; mt++)
      af[mt] = *(const i32x4*)&As[(wr * 64 + mt * 16 + c) * 80 + quad * 16];
    #pragma unroll
    for (int nt = 0; nt < 4; nt++)
      bf[nt] = *(const i32x4*)&Bs[(wc * 64 + nt * 16 + c) * 80 + quad * 16];
    #pragma unroll
    for (int mt = 0; mt < 4; mt++)
      #pragma unroll
      for (int nt = 0; nt < 4; nt++)
        acc[mt][nt] = __builtin_amdgcn_mfma_i32_16x16x64_i8(af[mt], bf[nt], acc[mt][nt], 0, 0, 0);
  }
  const float wsc = stats[2 * widx + 1];
  #pragma unroll
  for (int mt = 0; mt < 4; mt++)
    #pragma unroll
    for (int j = 0; j < 4; j++) {
      int m = row0 + wr * 64 + mt * 16 + quad * 4 + j;
      float rowscale = xs[m] * wsc;
      #pragma unroll
      for (int nt = 0; nt < 4; nt++)
        C[(size_t)m * Nc + col0 + wc * 64 + nt * 16 + c] = (float)acc[mt][nt][j] * rowscale;
    }
}

__global__ __launch_bounds__(256) void gemm_one(
    const int8_t* __restrict__ A, const int8_t* __restrict__ Bm,
    const float* __restrict__ xs, const float* __restrict__ stats, int widx,
    float* __restrict__ C, int Nc, int K)
{
  gemm_core(A, Bm, xs, stats, widx, C, Nc, K, blockIdx.x, blockIdx.y);
}

__global__ __launch_bounds__(256) void gemm_kv(
    const int8_t* __restrict__ A0, const int8_t* __restrict__ B0,
    const float* __restrict__ xs0, float* __restrict__ C0,
    const int8_t* __restrict__ A1, const int8_t* __restrict__ B1,
    const float* __restrict__ xs1, float* __restrict__ C1,
    const float* __restrict__ stats)
{
  if (blockIdx.z == 0)
    gemm_core(A0, B0, xs0, stats, 1, C0, KVd, Ee, blockIdx.x, blockIdx.y);
  else
    gemm_core(A1, B1, xs1, stats, 2, C1, KVd, Ee, blockIdx.x, blockIdx.y);
}

// ---------------- Pk fp32 [tok][512] -> packed f16 K fragments ----------------
// Layout: [bh][g16 = tok/16][kc=0..3][lane=0..63][8 halves]; chunk = 1 KB.
__global__ __launch_bounds__(256) void k_pack(
    const float* __restrict__ pk, _Float16* __restrict__ kp)
{
  __shared__ __align__(16) _Float16 lt[128][136];
  const int bh = blockIdx.x;      // b*4+h
  const int gq = blockIdx.y;      // 128-token chunk
  const int b = bh >> 2, h = bh & 3;
  const int tid = threadIdx.x;
  const int col = (tid & 31) * 4, r0 = tid >> 5;
  const float* src = pk + ((size_t)(b * Nn + gq * 128)) * KVd + h * HDd;
  #pragma unroll
  for (int p = 0; p < 16; p++) {
    int r = r0 + p * 8;
    float4 v = *(const float4*)(src + (size_t)r * KVd + col);
    lt[r][col+0] = (_Float16)v.x; lt[r][col+1] = (_Float16)v.y;
    lt[r][col+2] = (_Float16)v.z; lt[r][col+3] = (_Float16)v.w;
  }
  __syncthreads();
  const int wave = tid >> 6, lane = tid & 63;
  const int c = lane & 15, quad = lane >> 4;
  #pragma unroll
  for (int q = 0; q < 8; q++) {
    int chunk = wave * 8 + q;       // 0..31
    int gi = chunk >> 2, kc = chunk & 3;
    half8 v = *(const half8*)&lt[gi * 16 + c][kc * 32 + quad * 8];
    *(half8*)(kp + ((((size_t)bh * 128 + gq * 8 + gi) * 4 + kc) << 9) + lane * 8) = v;
  }
}

// ---------------- Pv fp32 [tok][512] -> packed f16 V^T fragments ----------------
// Layout: [bh][st = s/64][chunk = g*2+x, 16 chunks][lane][8 halves]; chunk = 1 KB.
__global__ __launch_bounds__(256) void v_pack(
    const float* __restrict__ pv, _Float16* __restrict__ pvt)
{
  __shared__ __align__(16) _Float16 lt[128][72];
  const int st = blockIdx.x;          // s-tile (64 tokens)
  const int bh = blockIdx.y;          // b*4+h
  const int b = bh >> 2, h = bh & 3;
  const int t = threadIdx.x;
  const int dc = (t & 31) * 4, srow = t >> 5;
  #pragma unroll
  for (int p = 0; p < 8; p++) {
    int s = srow + 8 * p;
    float4 v = *(const float4*)(pv + (size_t)(b * Nn + st * 64 + s) * KVd + h * HDd + dc);
    lt[dc+0][s] = (_Float16)v.x; lt[dc+1][s] = (_Float16)v.y;
    lt[dc+2][s] = (_Float16)v.z; lt[dc+3][s] = (_Float16)v.w;
  }
  __syncthreads();
  const int wave = t >> 6, lane = t & 63;
  const int c = lane & 15, quad = lane >> 4;
  _Float16* ob = pvt + (((size_t)bh * 32 + st) << 13);   // 16 chunks * 512 halves
  #pragma unroll
  for (int q = 0; q < 4; q++) {
    int chunk = wave * 4 + q;      // 0..15 = g*2+x
    int g = chunk >> 1, x = chunk & 1;
    half8 v = *(const half8*)&lt[g * 16 + c][x * 32 + quad * 8];
    *(half8*)(ob + (chunk << 9) + lane * 8) = v;
  }
}

// ---------------- MFMA flash attention (TLP + in-register K/V prefetch ILP) ----------------
// R4 structure (16 q-rows/block, 4-wave split-S, 17.2 KB LDS, two 8-row merge
// phases) + R0's register prefetch: kb overwritten right after QK^T with the
// NEXT tile's K (regs dead after QK), vb overwritten after PV -> each tile's
// load latency hides under the previous tile's softmax+PV.  Softmax in exp2
// domain (log2e folded into Q scale) - one v_mul fewer per exp on the VALU
// critical chain; merge coefficients use exp2 in the same scaled domain.
// __launch_bounds__(256,3): VGPR cap 170 (R0's identical live set compiled to
// 132, no spill; (256,4)'s cap 128 would be too tight, (256,6) spilled badly).
// Grid (bh=16, qtile=128): wg id % 8 == bh % 8 -> (b,h) pinned to one XCD.
__global__ __launch_bounds__(256, 3) void attn_mfma(
    const float* __restrict__ Pq, const _Float16* __restrict__ Kpk,
    const _Float16* __restrict__ Vpk, float* __restrict__ AO)
{
  __shared__ __align__(16) char smem[17152];
  const int tid  = threadIdx.x;
  const int wave = tid >> 6;
  const int lane = tid & 63;
  const int c = lane & 15, quad = lane >> 4;
  const int bhid = blockIdx.x;            // b*4 + h
  const int h = bhid & 3, b = bhid >> 2;
  const int qrow0 = blockIdx.y << 4;
  const size_t tokbase = (size_t)b * Nn;

  _Float16* st = (_Float16*)(smem + wave * 2304);       // 16 x 72 halves, per wave
  float (*cbuf)[8][130] = (float (*)[8][130])smem;      // 16640 B (aliases st)
  float (*cml)[16][2]   = (float (*)[16][2])(smem + 16640);  // 512 B (no alias)

  // Q fragments in registers (group-sum, /128 and log2(e) folded -> exp2 domain)
  half8 qa[4];
  {
    const float qsc = 0.0078125f * 1.44269504088896f;
    const float* qp = Pq + (tokbase + qrow0 + c) * Ee + (2 * h) * HDd;
    #pragma unroll
    for (int kc = 0; kc < 4; kc++) {
      int k0 = kc * 32 + quad * 8;
      float4 u0 = *(const float4*)(qp + k0);
      float4 u1 = *(const float4*)(qp + k0 + 4);
      float4 w0 = *(const float4*)(qp + HDd + k0);
      float4 w1 = *(const float4*)(qp + HDd + k0 + 4);
      half8 q8;
      q8[0] = (_Float16)((u0.x + w0.x) * qsc);
      q8[1] = (_Float16)((u0.y + w0.y) * qsc);
      q8[2] = (_Float16)((u0.z + w0.z) * qsc);
      q8[3] = (_Float16)((u0.w + w0.w) * qsc);
      q8[4] = (_Float16)((u1.x + w1.x) * qsc);
      q8[5] = (_Float16)((u1.y + w1.y) * qsc);
      q8[6] = (_Float16)((u1.z + w1.z) * qsc);
      q8[7] = (_Float16)((u1.w + w1.w) * qsc);
      qa[kc] = q8;
    }
  }

  float4_t oa[8];
  #pragma unroll
  for (int g = 0; g < 8; g++) oa[g] = (float4_t){0.f, 0.f, 0.f, 0.f};
  float m_i[4] = {-1e30f, -1e30f, -1e30f, -1e30f};
  float l_i[4] = {0.f, 0.f, 0.f, 0.f};

  const _Float16* kpkBH = Kpk + ((size_t)bhid << 18);
  const _Float16* vpkBH = Vpk + ((size_t)bhid << 18);

  const int kt0 = wave * 8;
  // ---- prologue: resident K/V fragments for first tile ----
  half8 kb[4][4], vb[8][2];
  {
    const _Float16* kb_base = kpkBH + ((size_t)kt0 << 13);
    const _Float16* vb_base = vpkBH + ((size_t)kt0 << 13);
    #pragma unroll
    for (int nb = 0; nb < 4; nb++)
      #pragma unroll
      for (int kc = 0; kc < 4; kc++)
        kb[nb][kc] = *(const half8*)(kb_base + (((nb << 2) + kc) << 9) + lane * 8);
    #pragma unroll
    for (int g = 0; g < 8; g++) {
      vb[g][0] = *(const half8*)(vb_base + (((g << 1) + 0) << 9) + lane * 8);
      vb[g][1] = *(const half8*)(vb_base + (((g << 1) + 1) << 9) + lane * 8);
    }
  }

  for (int kt = kt0; kt < kt0 + 8; kt++) {
    const int ktn = (kt < kt0 + 7) ? kt + 1 : kt;
    const _Float16* kb_next = kpkBH + ((size_t)ktn << 13);
    const _Float16* vb_next = vpkBH + ((size_t)ktn << 13);
    // ---- S = Q K^T from resident kb ----
    float4_t sfr[4];
    #pragma unroll
    for (int nb = 0; nb < 4; nb++) {
      float4_t acc = (float4_t){0.f, 0.f, 0.f, 0.f};
      #pragma unroll
      for (int kc = 0; kc < 4; kc++)
        acc = __builtin_amdgcn_mfma_f32_16x16x32_f16(qa[kc], kb[nb][kc], acc, 0, 0, 0);
      sfr[nb] = acc;
    }
    // ---- prefetch next K tile (kb dead after QK; latency hidden by softmax+PV) ----
    #pragma unroll
    for (int nb = 0; nb < 4; nb++)
      #pragma unroll
      for (int kc = 0; kc < 4; kc++)
        kb[nb][kc] = *(const half8*)(kb_next + (((nb << 2) + kc) << 9) + lane * 8);
    // ---- online softmax in exp2 domain, DPP reductions (VALU only) ----
    float alpha[4];
    bool ch = false;
    #pragma unroll
    for (int j = 0; j < 4; j++) {
      float t = fmaxf(fmaxf(sfr[0][j], sfr[1][j]), fmaxf(sfr[2][j], sfr[3][j]));
      t = red16_max(t);
      float mnew = fmaxf(m_i[j], t);
      ch = ch || (mnew > m_i[j]);
      alpha[j] = exp2f(m_i[j] - mnew);
      m_i[j] = mnew;
    }
    float rs[4] = {0.f, 0.f, 0.f, 0.f};
    #pragma unroll
    for (int nb = 0; nb < 4; nb++)
      #pragma unroll
      for (int j = 0; j < 4; j++) {
        float pv = exp2f(sfr[nb][j] - m_i[j]);
        sfr[nb][j] = pv;
        rs[j] += pv;
      }
    #pragma unroll
    for (int j = 0; j < 4; j++) l_i[j] = l_i[j] * alpha[j] + red16_sum(rs[j]);
    // ---- P: C-layout -> wave-private LDS -> A-layout ----
    #pragma unroll
    for (int nb = 0; nb < 4; nb++)
      #pragma unroll
      for (int j = 0; j < 4; j++)
        st[(quad * 4 + j) * 72 + nb * 16 + c] = (_Float16)sfr[nb][j];
    half8 pa0 = *(const half8*)&st[c * 72 + quad * 8];
    half8 pa1 = *(const half8*)&st[c * 72 + 32 + quad * 8];
    // ---- O rescale (exact skip when no row-max changed) + PV from resident vb ----
    if (__any(ch)) {
      #pragma unroll
      for (int g = 0; g < 8; g++) {
        oa[g][0] *= alpha[0]; oa[g][1] *= alpha[1];
        oa[g][2] *= alpha[2]; oa[g][3] *= alpha[3];
      }
    }
    #pragma unroll
    for (int g = 0; g < 8; g++) {
      oa[g] = __builtin_amdgcn_mfma_f32_16x16x32_f16(pa0, vb[g][0], oa[g], 0, 0, 0);
      oa[g] = __builtin_amdgcn_mfma_f32_16x16x32_f16(pa1, vb[g][1], oa[g], 0, 0, 0);
    }
    // ---- prefetch next V tile (vb dead after PV) ----
    #pragma unroll
    for (int g = 0; g < 8; g++) {
      vb[g][0] = *(const half8*)(vb_next + (((g << 1) + 0) << 9) + lane * 8);
      vb[g][1] = *(const half8*)(vb_next + (((g << 1) + 1) << 9) + lane * 8);
    }
  }

  // ---- LDS alias switch: all waves done with their P tiles ----
  __syncthreads();
  if (c == 0) {
    #pragma unroll
    for (int j = 0; j < 4; j++) {
      cml[wave][quad * 4 + j][0] = m_i[j];
      cml[wave][quad * 4 + j][1] = l_i[j];
    }
  }

  // ---- merge the 4 split-S partials in two 8-row phases (exp2 domain) ----
  #pragma unroll
  for (int p = 0; p < 2; p++) {
    if ((quad >> 1) == p) {
      const int r = (quad & 1) * 4;
      #pragma unroll
      for (int g = 0; g < 8; g++)
        #pragma unroll
        for (int j = 0; j < 4; j++)
          cbuf[wave][r + j][g * 16 + c] = oa[g][j];
    }
    __syncthreads();
    {
      const int row  = tid >> 5;          // 0..7
      const int col0 = (tid & 31) * 4;    // 0..124
      const int grow = p * 8 + row;       // global row 0..15
      float mw0 = cml[0][grow][0], mw1 = cml[1][grow][0];
      float mw2 = cml[2][grow][0], mw3 = cml[3][grow][0];
      float M = fmaxf(fmaxf(mw0, mw1), fmaxf(mw2, mw3));
      float c0 = exp2f(mw0 - M), c1 = exp2f(mw1 - M);
      float c2 = exp2f(mw2 - M), c3 = exp2f(mw3 - M);
      float L = c0 * cml[0][grow][1] + c1 * cml[1][grow][1]
              + c2 * cml[2][grow][1] + c3 * cml[3][grow][1];
      float inv = 1.0f / L;
      float o[4];
      #pragma unroll
      for (int i = 0; i < 4; i++)
        o[i] = (c0 * cbuf[0][row][col0 + i] + c1 * cbuf[1][row][col0 + i]
              + c2 * cbuf[2][row][col0 + i] + c3 * cbuf[3][row][col0 + i]) * inv;
      float* op = AO + (tokbase + qrow0 + grow) * KVd + h * HDd + col0;
      float4 r0v; r0v.x = o[0]; r0v.y = o[1]; r0v.z = o[2]; r0v.w = o[3];
      *(float4*)op = r0v;
    }
    __syncthreads();   // before phase 1 overwrites cbuf
  }
}

// ---------------- fused LayerNorm + rmsnorm + int8 quant (dim=512) ----------------
__global__ __launch_bounds__(128) void ln_quant(
    const float* __restrict__ AO, const float* __restrict__ g, const float* __restrict__ be,
    int8_t* __restrict__ oq, float* __restrict__ dq)
{
  __shared__ float r0[128], r1[128];
  __shared__ float sb[2];
  const int t = blockIdx.x, tid = threadIdx.x;
  float4 a = ((const float4*)(AO + (size_t)t * KVd))[tid];
  float s  = a.x + a.y + a.z + a.w;
  float ss = a.x*a.x + a.y*a.y + a.z*a.z + a.w*a.w;
  r0[tid] = s; r1[tid] = ss;
  __syncthreads();
  for (int st = 64; st > 0; st >>= 1) {
    if (tid < st) { r0[tid] += r0[tid+st]; r1[tid] += r1[tid+st]; }
    __syncthreads();
  }
  if (tid == 0) {
    float mu  = r0[0] / (float)KVd;
    float var = r1[0] / (float)KVd - mu*mu;
    sb[0] = mu;
    sb[1] = 1.0f / sqrtf(var + 1e-5f);
  }
  __syncthreads();
  const float mu = sb[0], iv = sb[1];
  float4 gv = ((const float4*)g)[tid];
  float4 bv = ((const float4*)be)[tid];
  float4 y;
  y.x = (a.x - mu) * iv * gv.x + bv.x;
  y.y = (a.y - mu) * iv * gv.y + bv.y;
  y.z = (a.z - mu) * iv * gv.z + bv.z;
  y.w = (a.w - mu) * iv * gv.w + bv.w;
  float ss2 = y.x*y.x + y.y*y.y + y.z*y.z + y.w*y.w;
  float mx  = fmaxf(fmaxf(fabsf(y.x), fabsf(y.y)), fmaxf(fabsf(y.z), fabsf(y.w)));
  __syncthreads();
  r0[tid] = ss2; r1[tid] = mx;
  __syncthreads();
  for (int st = 64; st > 0; st >>= 1) {
    if (tid < st) { r0[tid] += r0[tid+st]; r1[tid] = fmaxf(r1[tid], r1[tid+st]); }
    __syncthreads();
  }
  if (tid == 0) {
    float nrm = sqrtf(r0[0]);
    float rn  = sqrtf((float)KVd) / fmaxf(nrm, 1e-12f);
    float sc  = 127.0f / fmaxf(r1[0] * rn, 1e-5f);
    sb[0] = rn; sb[1] = sc;
    dq[t] = 1.0f / sc;
  }
  __syncthreads();
  const float rn = sb[0], sc = sb[1];
  char4 o;
  o.x = (signed char)fmaxf(fminf(rintf((y.x*rn)*sc), 127.f), -128.f);
  o.y = (signed char)fmaxf(fminf(rintf((y.y*rn)*sc), 127.f), -128.f);
  o.z = (signed char)fmaxf(fminf(rintf((y.z*rn)*sc), 127.f), -128.f);
  o.w = (signed char)fmaxf(fminf(rintf((y.w*rn)*sc), 127.f), -128.f);
  ((char4*)(oq + (size_t)t * KVd))[tid] = o;
}

// ---------------- launch ----------------
extern "C" void kernel_launch(void* const* d_in, const int* in_sizes, int n_in,
                              void* d_out, int out_size, void* d_ws, size_t ws_size,
                              hipStream_t stream)
{
  (void)in_sizes; (void)n_in; (void)out_size; (void)ws_size;
  const float* query = (const float*)d_in[0];
  const float* key_  = (const float*)d_in[1];
  const float* value = (const float*)d_in[2];
  const float* w_q   = (const float*)d_in[3];
  const float* w_k   = (const float*)d_in[4];
  const float* w_v   = (const float*)d_in[5];
  const float* w_o   = (const float*)d_in[6];
  const float* ln_g  = (const float*)d_in[7];
  const float* ln_b  = (const float*)d_in[8];
  float* out = (float*)d_out;

  char* ws = (char*)d_ws;
  float*     stats = (float*)    (ws + OFF_STATS);
  int8_t*    s_q   = (int8_t*)   (ws + OFF_SQ);
  int8_t*    s_k   = (int8_t*)   (ws + OFF_SK);
  int8_t*    s_v   = (int8_t*)   (ws + OFF_SV);
  int8_t*    s_o   = (int8_t*)   (ws + OFF_SO);
  int8_t*    xq_q  = (int8_t*)   (ws + OFF_XQQ);
  int8_t*    xq_k  = (int8_t*)   (ws + OFF_XQK);
  int8_t*    xq_v  = (int8_t*)   (ws + OFF_XQV);
  float*     xs_q  = (float*)    (ws + OFF_XSQ);
  float*     xs_k  = (float*)    (ws + OFF_XSK);
  float*     xs_v  = (float*)    (ws + OFF_XSV);
  float*     Pq    = (float*)    (ws + OFF_PQ);
  float*     Pk    = (float*)    (ws + OFF_PK);
  float*     Pv    = (float*)    (ws + OFF_PV);
  double*    part  = (double*)   (ws + OFF_PART);
  _Float16*  Kpk   = (_Float16*) (ws + OFF_PKH);
  _Float16*  Vpk   = (_Float16*) (ws + OFF_PVT);
  float*     AO    = (float*)    (ws + OFF_AO);
  int8_t*    oq    = (int8_t*)   (ws + OFF_OQ);
  float*     os_   = (float*)    (ws + OFF_OS);

  weight_stats_part<<<dim3(SB, 4), dim3(256), 0, stream>>>(w_q, w_k, w_v, w_o, part);
  weight_stats_fin<<<dim3(1), dim3(64), 0, stream>>>(part, stats);

  quant_w<<<dim3((Ee*Ee)/256),  dim3(256), 0, stream>>>(w_q, s_q, Ee*Ee,  stats, 0);
  quant_w<<<dim3((KVd*Ee)/256), dim3(256), 0, stream>>>(w_k, s_k, KVd*Ee, stats, 1);
  quant_w<<<dim3((KVd*Ee)/256), dim3(256), 0, stream>>>(w_v, s_v, KVd*Ee, stats, 2);
  quant_w<<<dim3((Ee*KVd)/256), dim3(256), 0, stream>>>(w_o, s_o, Ee*KVd, stats, 3);

  act_quant_e<<<dim3(Tt), dim3(256), 0, stream>>>(query, xq_q, xs_q);
  act_quant_e<<<dim3(Tt), dim3(256), 0, stream>>>(key_,  xq_k, xs_k);
  act_quant_e<<<dim3(Tt), dim3(256), 0, stream>>>(value, xq_v, xs_v);

  gemm_one<<<dim3(Ee/128, Tt/128), dim3(256), 0, stream>>>(xq_q, s_q, xs_q, stats, 0, Pq, Ee, Ee);
  gemm_kv<<<dim3(KVd/128, Tt/128, 2), dim3(256), 0, stream>>>(
      xq_k, s_k, xs_k, Pk, xq_v, s_v, xs_v, Pv, stats);

  k_pack<<<dim3(Bb*KVH, Nn/128), dim3(256), 0, stream>>>(Pk, Kpk);
  v_pack<<<dim3(Nn/64, Bb*KVH), dim3(256), 0, stream>>>(Pv, Vpk);

  // grid x = bh so wg-id % 8 == bh % 8 -> (b,h) pinned to one XCD (K/V L2-resident)
  attn_mfma<<<dim3(Bb*KVH, Nn/16), dim3(256), 0, stream>>>(Pq, Kpk, Vpk, AO);

  ln_quant<<<dim3(Tt), dim3(128), 0, stream>>>(AO, ln_g, ln_b, oq, os_);

  gemm_one<<<dim3(Ee/128, Tt/128), dim3(256), 0, stream>>>(oq, s_o, os_, stats, 3, out, Ee, KVd);
}

// Round 9
// 334.444 us; speedup vs baseline: 1.8122x; 1.8122x over previous
//
#include <hip/hip_runtime.h>
#include <stdint.h>
#include <stddef.h>

// ---------------- problem constants ----------------
constexpr int Bb  = 4;
constexpr int Nn  = 2048;
constexpr int Ee  = 1024;    // embed dim
constexpr int KVd = 512;     // kv dim
constexpr int HDd = 128;     // head dim
constexpr int KVH = 4;       // kv heads
constexpr int Tt  = Bb * Nn; // 8192 tokens

typedef _Float16 half8 __attribute__((ext_vector_type(8)));
typedef float    float4_t __attribute__((ext_vector_type(4)));
typedef int      i32x4 __attribute__((ext_vector_type(4)));

// ---------------- workspace layout (bytes) ----------------
constexpr size_t OFF_STATS = 0;                                  // 8 floats
constexpr size_t OFF_SQ  = 256;                                  // 1 MB  int8 sign(w_q-mean)
constexpr size_t OFF_SK  = OFF_SQ  + (size_t)Ee*Ee;              // 512 KB
constexpr size_t OFF_SV  = OFF_SK  + (size_t)KVd*Ee;             // 512 KB
constexpr size_t OFF_SO  = OFF_SV  + (size_t)KVd*Ee;             // 512 KB
constexpr size_t OFF_XQQ = OFF_SO  + (size_t)Ee*KVd;             // 8 MB  int8 quant inputs
constexpr size_t OFF_XQK = OFF_XQQ + (size_t)Tt*Ee;
constexpr size_t OFF_XQV = OFF_XQK + (size_t)Tt*Ee;
constexpr size_t OFF_XSQ = OFF_XQV + (size_t)Tt*Ee;              // per-token dequant scales
constexpr size_t OFF_XSK = OFF_XSQ + (size_t)Tt*4;
constexpr size_t OFF_XSV = OFF_XSK + (size_t)Tt*4;
constexpr size_t OFF_PQ  = OFF_XSV + (size_t)Tt*4;               // 32 MB fp32 q-proj
constexpr size_t OFF_PK  = OFF_PQ  + (size_t)Tt*Ee*4;            // 16 MB
constexpr size_t OFF_PV  = OFF_PK  + (size_t)Tt*KVd*4;           // 16 MB
// aliases (regions dead by the time these are written):
constexpr size_t OFF_PKH = OFF_XQQ;                              // 8 MB f16 K packed (xq_q dead after gemm Q)
constexpr size_t OFF_PVT = OFF_XQK;                              // 8 MB f16 V packed (xq_k dead after gemm KV)
constexpr size_t OFF_AO  = OFF_PK;                               // 16 MB over Pk fp32 (dead after k_pack)
constexpr size_t OFF_OQ  = OFF_XQV;                              // 4 MB over XQV (dead after gemm KV)
constexpr size_t OFF_OS  = OFF_OQ + (size_t)Tt*KVd;              // 32 KB, still inside XQV
constexpr size_t OFF_PART = OFF_PQ;                              // 4 KB partials alias Pq (consumed first)

// ---------------- async global -> LDS (16 B per lane, zero VGPR staging) ----------------
__device__ __forceinline__ void gload_lds16(const _Float16* g, _Float16* l) {
  __builtin_amdgcn_global_load_lds(
      (const __attribute__((address_space(1))) uint32_t*)g,
      (__attribute__((address_space(3))) uint32_t*)l,
      16, 0, 0);
}

// ---------------- DPP 16-lane replicated reductions (VALU-only) ----------------
template <int CTRL>
__device__ __forceinline__ float dpp_f(float x) {
  int i = __builtin_bit_cast(int, x);
  i = __builtin_amdgcn_update_dpp(0, i, CTRL, 0xF, 0xF, true);
  return __builtin_bit_cast(float, i);
}
__device__ __forceinline__ float red16_max(float x) {
  x = fmaxf(x, dpp_f<0xB1>(x));    // quad_perm [1,0,3,2]  (xor 1)
  x = fmaxf(x, dpp_f<0x4E>(x));    // quad_perm [2,3,0,1]  (xor 2)
  x = fmaxf(x, dpp_f<0x141>(x));   // row_half_mirror
  x = fmaxf(x, dpp_f<0x140>(x));   // row_mirror
  return x;
}
__device__ __forceinline__ float red16_sum(float x) {
  x += dpp_f<0xB1>(x);
  x += dpp_f<0x4E>(x);
  x += dpp_f<0x141>(x);
  x += dpp_f<0x140>(x);
  return x;
}

// ---------------- weight stats, stage 1 ----------------
constexpr int SB = 64;  // stat blocks per matrix

__global__ __launch_bounds__(256) void weight_stats_part(
    const float* __restrict__ w0, const float* __restrict__ w1,
    const float* __restrict__ w2, const float* __restrict__ w3,
    double* __restrict__ partials)
{
  const float* w; int n;
  switch (blockIdx.y) {
    case 0:  w = w0; n = Ee*Ee;  break;
    case 1:  w = w1; n = KVd*Ee; break;
    case 2:  w = w2; n = KVd*Ee; break;
    default: w = w3; n = Ee*KVd; break;
  }
  const int nv = n >> 2;
  double s = 0.0, sa = 0.0;
  for (int i = blockIdx.x * 256 + threadIdx.x; i < nv; i += SB * 256) {
    float4 v = ((const float4*)w)[i];
    s  += (double)v.x + (double)v.y + (double)v.z + (double)v.w;
    sa += (double)fabsf(v.x) + (double)fabsf(v.y) + (double)fabsf(v.z) + (double)fabsf(v.w);
  }
  __shared__ double r0[256], r1[256];
  r0[threadIdx.x] = s; r1[threadIdx.x] = sa;
  __syncthreads();
  for (int st = 128; st > 0; st >>= 1) {
    if (threadIdx.x < st) { r0[threadIdx.x] += r0[threadIdx.x+st]; r1[threadIdx.x] += r1[threadIdx.x+st]; }
    __syncthreads();
  }
  if (threadIdx.x == 0) {
    size_t o = ((size_t)blockIdx.y * SB + blockIdx.x) * 2;
    partials[o]   = r0[0];
    partials[o+1] = r1[0];
  }
}

__global__ __launch_bounds__(64) void weight_stats_fin(
    const double* __restrict__ partials, float* __restrict__ stats)
{
  int m = threadIdx.x;
  if (m < 4) {
    double s = 0.0, sa = 0.0;
    for (int i = 0; i < SB; i++) {
      s  += partials[((size_t)m * SB + i) * 2];
      sa += partials[((size_t)m * SB + i) * 2 + 1];
    }
    int n = (m == 0) ? Ee*Ee : (m == 3 ? Ee*KVd : KVd*Ee);
    stats[2*m]   = (float)(s  / n);
    stats[2*m+1] = (float)(sa / n);
  }
}

// ---------------- ternary weight signs ----------------
__global__ __launch_bounds__(256) void quant_w(
    const float* __restrict__ w, int8_t* __restrict__ s, int n,
    const float* __restrict__ stats, int idx)
{
  int i = blockIdx.x * 256 + threadIdx.x;
  if (i < n) {
    float d = w[i] - stats[2*idx];
    s[i] = (d > 0.f) ? (int8_t)1 : ((d < 0.f) ? (int8_t)-1 : (int8_t)0);
  }
}

// ---------------- fused rmsnorm + int8 act quant (dim=1024) ----------------
__global__ __launch_bounds__(256) void act_quant_e(
    const float* __restrict__ x, int8_t* __restrict__ q, float* __restrict__ dq)
{
  __shared__ float r0[256], r1[256];
  __shared__ float sb[2];
  const int t = blockIdx.x, tid = threadIdx.x;
  float4 a = ((const float4*)(x + (size_t)t * Ee))[tid];
  float ss = a.x*a.x + a.y*a.y + a.z*a.z + a.w*a.w;
  float mx = fmaxf(fmaxf(fabsf(a.x), fabsf(a.y)), fmaxf(fabsf(a.z), fabsf(a.w)));
  r0[tid] = ss; r1[tid] = mx;
  __syncthreads();
  for (int st = 128; st > 0; st >>= 1) {
    if (tid < st) { r0[tid] += r0[tid+st]; r1[tid] = fmaxf(r1[tid], r1[tid+st]); }
    __syncthreads();
  }
  if (tid == 0) {
    float nrm = sqrtf(r0[0]);
    float rn  = sqrtf((float)Ee) / fmaxf(nrm, 1e-12f);
    float sc  = 127.0f / fmaxf(r1[0] * rn, 1e-5f);
    sb[0] = rn; sb[1] = sc;
    dq[t] = 1.0f / sc;
  }
  __syncthreads();
  const float rn = sb[0], sc = sb[1];
  char4 o;
  o.x = (signed char)fmaxf(fminf(rintf((a.x*rn)*sc), 127.f), -128.f);
  o.y = (signed char)fmaxf(fminf(rintf((a.y*rn)*sc), 127.f), -128.f);
  o.z = (signed char)fmaxf(fminf(rintf((a.z*rn)*sc), 127.f), -128.f);
  o.w = (signed char)fmaxf(fminf(rintf((a.w*rn)*sc), 127.f), -128.f);
  ((char4*)(q + (size_t)t * Ee))[tid] = o;
}

// ---------------- int8 x ternary GEMM via MFMA (exact i32 accumulate) ----------------
// 2-phase pipelined: loads for tile k+1 issued AFTER the barrier, BEFORE the
// MFMA cluster of tile k, so global latency hides under MFMAs (T3 minimal).
__device__ __forceinline__ void gemm_core(
    const int8_t* __restrict__ A, const int8_t* __restrict__ Bm,
    const float* __restrict__ xs, const float* __restrict__ stats, int widx,
    float* __restrict__ C, int Nc, int K, int bx, int by)
{
  __shared__ int8_t As[128 * 80];   // 80-B padded rows
  __shared__ int8_t Bs[128 * 80];
  const int tid = threadIdx.x;
  const int row0 = by * 128, col0 = bx * 128;
  const int lane = tid & 63, wave = tid >> 6;
  const int wr = wave >> 1, wc = wave & 1;
  const int c = lane & 15, quad = lane >> 4;

  i32x4 acc[4][4];
  #pragma unroll
  for (int mt = 0; mt < 4; mt++)
    #pragma unroll
    for (int nt = 0; nt < 4; nt++) acc[mt][nt] = (i32x4){0, 0, 0, 0};

  const int srow = tid >> 2;
  const int schunk = (tid & 3) * 16;
  const int8_t* pa0 = A  + (size_t)(row0 + srow)      * K + schunk;
  const int8_t* pa1 = A  + (size_t)(row0 + 64 + srow) * K + schunk;
  const int8_t* pb0 = Bm + (size_t)(col0 + srow)      * K + schunk;
  const int8_t* pb1 = Bm + (size_t)(col0 + 64 + srow) * K + schunk;

  int4 a0 = *(const int4*)(pa0);
  int4 a1 = *(const int4*)(pa1);
  int4 b0 = *(const int4*)(pb0);
  int4 b1 = *(const int4*)(pb1);

  for (int k0 = 0; k0 < K; k0 += 64) {
    __syncthreads();
    *(int4*)&As[srow * 80 + schunk]        = a0;
    *(int4*)&As[(64 + srow) * 80 + schunk] = a1;
    *(int4*)&Bs[srow * 80 + schunk]        = b0;
    *(int4*)&Bs[(64 + srow) * 80 + schunk] = b1;
    __syncthreads();
    // issue next-tile loads before MFMA cluster (latency hidden by MFMAs)
    const int kn = (k0 + 64 < K) ? k0 + 64 : k0;
    a0 = *(const int4*)(pa0 + kn);
    a1 = *(const int4*)(pa1 + kn);
    b0 = *(const int4*)(pb0 + kn);
    b1 = *(const int4*)(pb1 + kn);
    i32x4 af[4], bf[4];
    #pragma unroll
    for (int mt = 0; mt < 4; mt++)
      af[mt] = *(const i32x4*)&As[(wr * 64 + mt * 16 + c) * 80 + quad * 16];
    #pragma unroll
    for (int nt = 0; nt < 4; nt++)
      bf[nt] = *(const i32x4*)&Bs[(wc * 64 + nt * 16 + c) * 80 + quad * 16];
    #pragma unroll
    for (int mt = 0; mt < 4; mt++)
      #pragma unroll
      for (int nt = 0; nt < 4; nt++)
        acc[mt][nt] = __builtin_amdgcn_mfma_i32_16x16x64_i8(af[mt], bf[nt], acc[mt][nt], 0, 0, 0);
  }
  const float wsc = stats[2 * widx + 1];
  #pragma unroll
  for (int mt = 0; mt < 4; mt++)
    #pragma unroll
    for (int j = 0; j < 4; j++) {
      int m = row0 + wr * 64 + mt * 16 + quad * 4 + j;
      float rowscale = xs[m] * wsc;
      #pragma unroll
      for (int nt = 0; nt < 4; nt++)
        C[(size_t)m * Nc + col0 + wc * 64 + nt * 16 + c] = (float)acc[mt][nt][j] * rowscale;
    }
}

__global__ __launch_bounds__(256) void gemm_one(
    const int8_t* __restrict__ A, const int8_t* __restrict__ Bm,
    const float* __restrict__ xs, const float* __restrict__ stats, int widx,
    float* __restrict__ C, int Nc, int K)
{
  gemm_core(A, Bm, xs, stats, widx, C, Nc, K, blockIdx.x, blockIdx.y);
}

__global__ __launch_bounds__(256) void gemm_kv(
    const int8_t* __restrict__ A0, const int8_t* __restrict__ B0,
    const float* __restrict__ xs0, float* __restrict__ C0,
    const int8_t* __restrict__ A1, const int8_t* __restrict__ B1,
    const float* __restrict__ xs1, float* __restrict__ C1,
    const float* __restrict__ stats)
{
  if (blockIdx.z == 0)
    gemm_core(A0, B0, xs0, stats, 1, C0, KVd, Ee, blockIdx.x, blockIdx.y);
  else
    gemm_core(A1, B1, xs1, stats, 2, C1, KVd, Ee, blockIdx.x, blockIdx.y);
}

// ---------------- Pk fp32 [tok][512] -> packed f16 K fragments ----------------
// Layout: [bh][g16 = tok/16][kc=0..3][lane=0..63][8 halves]; chunk = 1 KB.
__global__ __launch_bounds__(256) void k_pack(
    const float* __restrict__ pk, _Float16* __restrict__ kp)
{
  __shared__ __align__(16) _Float16 lt[128][136];
  const int bh = blockIdx.x;      // b*4+h
  const int gq = blockIdx.y;      // 128-token chunk
  const int b = bh >> 2, h = bh & 3;
  const int tid = threadIdx.x;
  const int col = (tid & 31) * 4, r0 = tid >> 5;
  const float* src = pk + ((size_t)(b * Nn + gq * 128)) * KVd + h * HDd;
  #pragma unroll
  for (int p = 0; p < 16; p++) {
    int r = r0 + p * 8;
    float4 v = *(const float4*)(src + (size_t)r * KVd + col);
    lt[r][col+0] = (_Float16)v.x; lt[r][col+1] = (_Float16)v.y;
    lt[r][col+2] = (_Float16)v.z; lt[r][col+3] = (_Float16)v.w;
  }
  __syncthreads();
  const int wave = tid >> 6, lane = tid & 63;
  const int c = lane & 15, quad = lane >> 4;
  #pragma unroll
  for (int q = 0; q < 8; q++) {
    int chunk = wave * 8 + q;       // 0..31
    int gi = chunk >> 2, kc = chunk & 3;
    half8 v = *(const half8*)&lt[gi * 16 + c][kc * 32 + quad * 8];
    *(half8*)(kp + ((((size_t)bh * 128 + gq * 8 + gi) * 4 + kc) << 9) + lane * 8) = v;
  }
}

// ---------------- Pv fp32 [tok][512] -> packed f16 V^T fragments ----------------
// Layout: [bh][st = s/64][chunk = g*2+x, 16 chunks][lane][8 halves]; chunk = 1 KB.
__global__ __launch_bounds__(256) void v_pack(
    const float* __restrict__ pv, _Float16* __restrict__ pvt)
{
  __shared__ __align__(16) _Float16 lt[128][72];
  const int st = blockIdx.x;          // s-tile (64 tokens)
  const int bh = blockIdx.y;          // b*4+h
  const int b = bh >> 2, h = bh & 3;
  const int t = threadIdx.x;
  const int dc = (t & 31) * 4, srow = t >> 5;
  #pragma unroll
  for (int p = 0; p < 8; p++) {
    int s = srow + 8 * p;
    float4 v = *(const float4*)(pv + (size_t)(b * Nn + st * 64 + s) * KVd + h * HDd + dc);
    lt[dc+0][s] = (_Float16)v.x; lt[dc+1][s] = (_Float16)v.y;
    lt[dc+2][s] = (_Float16)v.z; lt[dc+3][s] = (_Float16)v.w;
  }
  __syncthreads();
  const int wave = t >> 6, lane = t & 63;
  const int c = lane & 15, quad = lane >> 4;
  _Float16* ob = pvt + (((size_t)bh * 32 + st) << 13);   // 16 chunks * 512 halves
  #pragma unroll
  for (int q = 0; q < 4; q++) {
    int chunk = wave * 4 + q;      // 0..15 = g*2+x
    int g = chunk >> 1, x = chunk & 1;
    half8 v = *(const half8*)&lt[g * 16 + c][x * 32 + quad * 8];
    *(half8*)(ob + (chunk << 9) + lane * 8) = v;
  }
}

// ---------------- MFMA flash attention (async LDS-staged K+V, m97 schedule) ----------------
// Block = 64 q-rows (4 waves x 16, NO split-S, no merge), full 32-tile sweep.
// Per tile: K (16 KB) + V (16 KB) staged into double-buffered shared LDS via
// global_load_lds (ZERO staging VGPRs, async, counted by vmcnt).  Each wave
// issues 8 of the 32 1-KB chunks for tile t+1, then computes tile t from LDS
// (conflict-free ds_read_b128).  One __syncthreads per tile (its implicit
// vmcnt(0) drain is free: loads had the whole previous tile to land).
// K/V L2 traffic /4 vs R4 (shared by 4 waves); no serial load chain per wave.
// LDS 74.75 KB -> 2 blocks/CU; (256,2) caps VGPR at 256 -> no spill possible.
// Grid (bh=16, qtile=32): wg id % 8 == bh % 8 -> (b,h) pinned to one XCD.
__global__ __launch_bounds__(256, 2) void attn_mfma(
    const float* __restrict__ Pq, const _Float16* __restrict__ Kpk,
    const _Float16* __restrict__ Vpk, float* __restrict__ AO)
{
  __shared__ __align__(16) _Float16 kv[2][16384];    // [buf][K 16KB | V 16KB]
  __shared__ __align__(16) _Float16 stile[4][1152];  // per-wave P transpose
  const int tid  = threadIdx.x;
  const int wave = tid >> 6;
  const int lane = tid & 63;
  const int c = lane & 15, quad = lane >> 4;
  const int bhid = blockIdx.x;            // b*4 + h
  const int h = bhid & 3, b = bhid >> 2;
  const int qrow0 = (blockIdx.y << 6) + wave * 16;   // 64 rows/block, 16/wave
  const size_t tokbase = (size_t)b * Nn;

  _Float16* st = stile[wave];

  // Q fragments in registers (group-sum, /128 and log2(e) folded -> exp2 domain)
  half8 qa[4];
  {
    const float qsc = 0.0078125f * 1.44269504088896f;
    const float* qp = Pq + (tokbase + qrow0 + c) * Ee + (2 * h) * HDd;
    #pragma unroll
    for (int kc = 0; kc < 4; kc++) {
      int k0 = kc * 32 + quad * 8;
      float4 u0 = *(const float4*)(qp + k0);
      float4 u1 = *(const float4*)(qp + k0 + 4);
      float4 w0 = *(const float4*)(qp + HDd + k0);
      float4 w1 = *(const float4*)(qp + HDd + k0 + 4);
      half8 q8;
      q8[0] = (_Float16)((u0.x + w0.x) * qsc);
      q8[1] = (_Float16)((u0.y + w0.y) * qsc);
      q8[2] = (_Float16)((u0.z + w0.z) * qsc);
      q8[3] = (_Float16)((u0.w + w0.w) * qsc);
      q8[4] = (_Float16)((u1.x + w1.x) * qsc);
      q8[5] = (_Float16)((u1.y + w1.y) * qsc);
      q8[6] = (_Float16)((u1.z + w1.z) * qsc);
      q8[7] = (_Float16)((u1.w + w1.w) * qsc);
      qa[kc] = q8;
    }
  }

  float4_t oa[8];
  #pragma unroll
  for (int g = 0; g < 8; g++) oa[g] = (float4_t){0.f, 0.f, 0.f, 0.f};
  float m_i[4] = {-1e30f, -1e30f, -1e30f, -1e30f};
  float l_i[4] = {0.f, 0.f, 0.f, 0.f};

  const _Float16* kpkBH = Kpk + ((size_t)bhid << 18);
  const _Float16* vpkBH = Vpk + ((size_t)bhid << 18);

  // this wave's 8 staging chunks: waves 0-1 -> K chunks 0..15, waves 2-3 -> V 0..15
  const int ci0 = wave * 8;

  // ---- prologue: stage tile 0 into buf 0 ----
  {
    #pragma unroll
    for (int q = 0; q < 8; q++) {
      const int ci = ci0 + q;
      const _Float16* gsrc = ((ci < 16) ? (kpkBH + ((size_t)ci << 9))
                                        : (vpkBH + ((size_t)(ci - 16) << 9))) + lane * 8;
      gload_lds16(gsrc, &kv[0][(size_t)ci << 9]);
    }
  }
  __syncthreads();   // implicit vmcnt(0) drain: tile 0 resident

  for (int kt = 0; kt < 32; kt++) {
    const int cur = kt & 1;
    // ---- issue async stage of tile kt+1 into the other buffer ----
    if (kt < 31) {
      const size_t tb = (size_t)(kt + 1) << 13;
      #pragma unroll
      for (int q = 0; q < 8; q++) {
        const int ci = ci0 + q;
        const _Float16* gsrc = ((ci < 16) ? (kpkBH + tb + ((size_t)ci << 9))
                                          : (vpkBH + tb + ((size_t)(ci - 16) << 9))) + lane * 8;
        gload_lds16(gsrc, &kv[cur ^ 1][(size_t)ci << 9]);
      }
    }
    const _Float16* kvc = &kv[cur][0];
    // ---- K fragments from shared LDS (conflict-free ds_read_b128) ----
    // ---- S = Q K^T ----
    float4_t sfr[4];
    #pragma unroll
    for (int nb = 0; nb < 4; nb++) {
      float4_t acc = (float4_t){0.f, 0.f, 0.f, 0.f};
      #pragma unroll
      for (int kc = 0; kc < 4; kc++) {
        half8 kf = *(const half8*)&kvc[(((nb << 2) + kc) << 9) + lane * 8];
        acc = __builtin_amdgcn_mfma_f32_16x16x32_f16(qa[kc], kf, acc, 0, 0, 0);
      }
      sfr[nb] = acc;
    }
    // ---- online softmax in exp2 domain, DPP reductions (VALU only) ----
    float alpha[4];
    bool ch = false;
    #pragma unroll
    for (int j = 0; j < 4; j++) {
      float t = fmaxf(fmaxf(sfr[0][j], sfr[1][j]), fmaxf(sfr[2][j], sfr[3][j]));
      t = red16_max(t);
      float mnew = fmaxf(m_i[j], t);
      ch = ch || (mnew > m_i[j]);
      alpha[j] = exp2f(m_i[j] - mnew);
      m_i[j] = mnew;
    }
    float rs[4] = {0.f, 0.f, 0.f, 0.f};
    #pragma unroll
    for (int nb = 0; nb < 4; nb++)
      #pragma unroll
      for (int j = 0; j < 4; j++) {
        float pv = exp2f(sfr[nb][j] - m_i[j]);
        sfr[nb][j] = pv;
        rs[j] += pv;
      }
    #pragma unroll
    for (int j = 0; j < 4; j++) l_i[j] = l_i[j] * alpha[j] + red16_sum(rs[j]);
    // ---- P: C-layout -> wave-private LDS -> A-layout ----
    #pragma unroll
    for (int nb = 0; nb < 4; nb++)
      #pragma unroll
      for (int j = 0; j < 4; j++)
        st[(quad * 4 + j) * 72 + nb * 16 + c] = (_Float16)sfr[nb][j];
    half8 pa0 = *(const half8*)&st[c * 72 + quad * 8];
    half8 pa1 = *(const half8*)&st[c * 72 + 32 + quad * 8];
    // ---- O rescale (exact skip when no row-max changed) + PV from LDS V ----
    if (__any(ch)) {
      #pragma unroll
      for (int g = 0; g < 8; g++) {
        oa[g][0] *= alpha[0]; oa[g][1] *= alpha[1];
        oa[g][2] *= alpha[2]; oa[g][3] *= alpha[3];
      }
    }
    #pragma unroll
    for (int g = 0; g < 8; g++) {
      half8 v0 = *(const half8*)&kvc[((16 + (g << 1) + 0) << 9) + lane * 8];
      half8 v1 = *(const half8*)&kvc[((16 + (g << 1) + 1) << 9) + lane * 8];
      oa[g] = __builtin_amdgcn_mfma_f32_16x16x32_f16(pa0, v0, oa[g], 0, 0, 0);
      oa[g] = __builtin_amdgcn_mfma_f32_16x16x32_f16(pa1, v1, oa[g], 0, 0, 0);
    }
    // ---- tile boundary: drains this tile's stage loads (issued ~1 tile ago) ----
    __syncthreads();
  }

  // ---- epilogue: each wave writes its own 16 rows (no merge) ----
  float invl[4];
  #pragma unroll
  for (int j = 0; j < 4; j++) invl[j] = 1.0f / l_i[j];
  #pragma unroll
  for (int g = 0; g < 8; g++)
    #pragma unroll
    for (int j = 0; j < 4; j++)
      AO[(tokbase + qrow0 + quad * 4 + j) * KVd + h * HDd + g * 16 + c] = oa[g][j] * invl[j];
}

// ---------------- fused LayerNorm + rmsnorm + int8 quant (dim=512) ----------------
__global__ __launch_bounds__(128) void ln_quant(
    const float* __restrict__ AO, const float* __restrict__ g, const float* __restrict__ be,
    int8_t* __restrict__ oq, float* __restrict__ dq)
{
  __shared__ float r0[128], r1[128];
  __shared__ float sb[2];
  const int t = blockIdx.x, tid = threadIdx.x;
  float4 a = ((const float4*)(AO + (size_t)t * KVd))[tid];
  float s  = a.x + a.y + a.z + a.w;
  float ss = a.x*a.x + a.y*a.y + a.z*a.z + a.w*a.w;
  r0[tid] = s; r1[tid] = ss;
  __syncthreads();
  for (int st = 64; st > 0; st >>= 1) {
    if (tid < st) { r0[tid] += r0[tid+st]; r1[tid] += r1[tid+st]; }
    __syncthreads();
  }
  if (tid == 0) {
    float mu  = r0[0] / (float)KVd;
    float var = r1[0] / (float)KVd - mu*mu;
    sb[0] = mu;
    sb[1] = 1.0f / sqrtf(var + 1e-5f);
  }
  __syncthreads();
  const float mu = sb[0], iv = sb[1];
  float4 gv = ((const float4*)g)[tid];
  float4 bv = ((const float4*)be)[tid];
  float4 y;
  y.x = (a.x - mu) * iv * gv.x + bv.x;
  y.y = (a.y - mu) * iv * gv.y + bv.y;
  y.z = (a.z - mu) * iv * gv.z + bv.z;
  y.w = (a.w - mu) * iv * gv.w + bv.w;
  float ss2 = y.x*y.x + y.y*y.y + y.z*y.z + y.w*y.w;
  float mx  = fmaxf(fmaxf(fabsf(y.x), fabsf(y.y)), fmaxf(fabsf(y.z), fabsf(y.w)));
  __syncthreads();
  r0[tid] = ss2; r1[tid] = mx;
  __syncthreads();
  for (int st = 64; st > 0; st >>= 1) {
    if (tid < st) { r0[tid] += r0[tid+st]; r1[tid] = fmaxf(r1[tid], r1[tid+st]); }
    __syncthreads();
  }
  if (tid == 0) {
    float nrm = sqrtf(r0[0]);
    float rn  = sqrtf((float)KVd) / fmaxf(nrm, 1e-12f);
    float sc  = 127.0f / fmaxf(r1[0] * rn, 1e-5f);
    sb[0] = rn; sb[1] = sc;
    dq[t] = 1.0f / sc;
  }
  __syncthreads();
  const float rn = sb[0], sc = sb[1];
  char4 o;
  o.x = (signed char)fmaxf(fminf(rintf((y.x*rn)*sc), 127.f), -128.f);
  o.y = (signed char)fmaxf(fminf(rintf((y.y*rn)*sc), 127.f), -128.f);
  o.z = (signed char)fmaxf(fminf(rintf((y.z*rn)*sc), 127.f), -128.f);
  o.w = (signed char)fmaxf(fminf(rintf((y.w*rn)*sc), 127.f), -128.f);
  ((char4*)(oq + (size_t)t * KVd))[tid] = o;
}

// ---------------- launch ----------------
extern "C" void kernel_launch(void* const* d_in, const int* in_sizes, int n_in,
                              void* d_out, int out_size, void* d_ws, size_t ws_size,
                              hipStream_t stream)
{
  (void)in_sizes; (void)n_in; (void)out_size; (void)ws_size;
  const float* query = (const float*)d_in[0];
  const float* key_  = (const float*)d_in[1];
  const float* value = (const float*)d_in[2];
  const float* w_q   = (const float*)d_in[3];
  const float* w_k   = (const float*)d_in[4];
  const float* w_v   = (const float*)d_in[5];
  const float* w_o   = (const float*)d_in[6];
  const float* ln_g  = (const float*)d_in[7];
  const float* ln_b  = (const float*)d_in[8];
  float* out = (float*)d_out;

  char* ws = (char*)d_ws;
  float*     stats = (float*)    (ws + OFF_STATS);
  int8_t*    s_q   = (int8_t*)   (ws + OFF_SQ);
  int8_t*    s_k   = (int8_t*)   (ws + OFF_SK);
  int8_t*    s_v   = (int8_t*)   (ws + OFF_SV);
  int8_t*    s_o   = (int8_t*)   (ws + OFF_SO);
  int8_t*    xq_q  = (int8_t*)   (ws + OFF_XQQ);
  int8_t*    xq_k  = (int8_t*)   (ws + OFF_XQK);
  int8_t*    xq_v  = (int8_t*)   (ws + OFF_XQV);
  float*     xs_q  = (float*)    (ws + OFF_XSQ);
  float*     xs_k  = (float*)    (ws + OFF_XSK);
  float*     xs_v  = (float*)    (ws + OFF_XSV);
  float*     Pq    = (float*)    (ws + OFF_PQ);
  float*     Pk    = (float*)    (ws + OFF_PK);
  float*     Pv    = (float*)    (ws + OFF_PV);
  double*    part  = (double*)   (ws + OFF_PART);
  _Float16*  Kpk   = (_Float16*) (ws + OFF_PKH);
  _Float16*  Vpk   = (_Float16*) (ws + OFF_PVT);
  float*     AO    = (float*)    (ws + OFF_AO);
  int8_t*    oq    = (int8_t*)   (ws + OFF_OQ);
  float*     os_   = (float*)    (ws + OFF_OS);

  weight_stats_part<<<dim3(SB, 4), dim3(256), 0, stream>>>(w_q, w_k, w_v, w_o, part);
  weight_stats_fin<<<dim3(1), dim3(64), 0, stream>>>(part, stats);

  quant_w<<<dim3((Ee*Ee)/256),  dim3(256), 0, stream>>>(w_q, s_q, Ee*Ee,  stats, 0);
  quant_w<<<dim3((KVd*Ee)/256), dim3(256), 0, stream>>>(w_k, s_k, KVd*Ee, stats, 1);
  quant_w<<<dim3((KVd*Ee)/256), dim3(256), 0, stream>>>(w_v, s_v, KVd*Ee, stats, 2);
  quant_w<<<dim3((Ee*KVd)/256), dim3(256), 0, stream>>>(w_o, s_o, Ee*KVd, stats, 3);

  act_quant_e<<<dim3(Tt), dim3(256), 0, stream>>>(query, xq_q, xs_q);
  act_quant_e<<<dim3(Tt), dim3(256), 0, stream>>>(key_,  xq_k, xs_k);
  act_quant_e<<<dim3(Tt), dim3(256), 0, stream>>>(value, xq_v, xs_v);

  gemm_one<<<dim3(Ee/128, Tt/128), dim3(256), 0, stream>>>(xq_q, s_q, xs_q, stats, 0, Pq, Ee, Ee);
  gemm_kv<<<dim3(KVd/128, Tt/128, 2), dim3(256), 0, stream>>>(
      xq_k, s_k, xs_k, Pk, xq_v, s_v, xs_v, Pv, stats);

  k_pack<<<dim3(Bb*KVH, Nn/128), dim3(256), 0, stream>>>(Pk, Kpk);
  v_pack<<<dim3(Nn/64, Bb*KVH), dim3(256), 0, stream>>>(Pv, Vpk);

  // grid x = bh so wg-id % 8 == bh % 8 -> (b,h) pinned to one XCD (K/V L2-resident)
  attn_mfma<<<dim3(Bb*KVH, Nn/64), dim3(256), 0, stream>>>(Pq, Kpk, Vpk, AO);

  ln_quant<<<dim3(Tt), dim3(128), 0, stream>>>(AO, ln_g, ln_b, oq, os_);

  gemm_one<<<dim3(Ee/128, Tt/128), dim3(256), 0, stream>>>(oq, s_o, os_, stats, 3, out, Ee, KVd);
}

// Round 10
// 313.402 us; speedup vs baseline: 1.9339x; 1.0671x over previous
//
#include <hip/hip_runtime.h>
#include <stdint.h>
#include <stddef.h>

// ---------------- problem constants ----------------
constexpr int Bb  = 4;
constexpr int Nn  = 2048;
constexpr int Ee  = 1024;    // embed dim
constexpr int KVd = 512;     // kv dim
constexpr int HDd = 128;     // head dim
constexpr int KVH = 4;       // kv heads
constexpr int Tt  = Bb * Nn; // 8192 tokens

typedef _Float16 half8 __attribute__((ext_vector_type(8)));
typedef float    float4_t __attribute__((ext_vector_type(4)));
typedef int      i32x4 __attribute__((ext_vector_type(4)));

// ---------------- workspace layout (bytes) ----------------
constexpr size_t OFF_STATS = 0;                                  // 8 floats
constexpr size_t OFF_SQ  = 256;                                  // 1 MB  int8 sign(w_q-mean)
constexpr size_t OFF_SK  = OFF_SQ  + (size_t)Ee*Ee;              // 512 KB
constexpr size_t OFF_SV  = OFF_SK  + (size_t)KVd*Ee;             // 512 KB
constexpr size_t OFF_SO  = OFF_SV  + (size_t)KVd*Ee;             // 512 KB
constexpr size_t OFF_XQQ = OFF_SO  + (size_t)Ee*KVd;             // 8 MB  int8 quant inputs
constexpr size_t OFF_XQK = OFF_XQQ + (size_t)Tt*Ee;
constexpr size_t OFF_XQV = OFF_XQK + (size_t)Tt*Ee;
constexpr size_t OFF_XSQ = OFF_XQV + (size_t)Tt*Ee;              // per-token dequant scales
constexpr size_t OFF_XSK = OFF_XSQ + (size_t)Tt*4;
constexpr size_t OFF_XSV = OFF_XSK + (size_t)Tt*4;
constexpr size_t OFF_PQ  = OFF_XSV + (size_t)Tt*4;               // 32 MB fp32 q-proj
constexpr size_t OFF_PK  = OFF_PQ  + (size_t)Tt*Ee*4;            // 16 MB
constexpr size_t OFF_PV  = OFF_PK  + (size_t)Tt*KVd*4;           // 16 MB
// aliases (regions dead by the time these are written):
constexpr size_t OFF_PKH = OFF_XQQ;                              // 8 MB f16 K packed (xq_q dead after gemm Q)
constexpr size_t OFF_PVT = OFF_XQK;                              // 8 MB f16 V packed (xq_k dead after gemm KV)
constexpr size_t OFF_AO  = OFF_PK;                               // 16 MB over Pk fp32 (dead after k_pack)
constexpr size_t OFF_OQ  = OFF_XQV;                              // 4 MB over XQV (dead after gemm KV)
constexpr size_t OFF_OS  = OFF_OQ + (size_t)Tt*KVd;              // 32 KB, still inside XQV
constexpr size_t OFF_PART = OFF_PQ;                              // 4 KB partials alias Pq (consumed first)

// ---------------- async global -> LDS (16 B per lane, zero VGPR staging) ----------------
__device__ __forceinline__ void gload_lds16(const _Float16* g, _Float16* l) {
  __builtin_amdgcn_global_load_lds(
      (const __attribute__((address_space(1))) uint32_t*)g,
      (__attribute__((address_space(3))) uint32_t*)l,
      16, 0, 0);
}

// ---------------- DPP 16-lane replicated reductions (VALU-only) ----------------
template <int CTRL>
__device__ __forceinline__ float dpp_f(float x) {
  int i = __builtin_bit_cast(int, x);
  i = __builtin_amdgcn_update_dpp(0, i, CTRL, 0xF, 0xF, true);
  return __builtin_bit_cast(float, i);
}
__device__ __forceinline__ float red16_max(float x) {
  x = fmaxf(x, dpp_f<0xB1>(x));    // quad_perm [1,0,3,2]  (xor 1)
  x = fmaxf(x, dpp_f<0x4E>(x));    // quad_perm [2,3,0,1]  (xor 2)
  x = fmaxf(x, dpp_f<0x141>(x));   // row_half_mirror
  x = fmaxf(x, dpp_f<0x140>(x));   // row_mirror
  return x;
}

// ---------------- weight stats, stage 1 ----------------
constexpr int SB = 64;  // stat blocks per matrix

__global__ __launch_bounds__(256) void weight_stats_part(
    const float* __restrict__ w0, const float* __restrict__ w1,
    const float* __restrict__ w2, const float* __restrict__ w3,
    double* __restrict__ partials)
{
  const float* w; int n;
  switch (blockIdx.y) {
    case 0:  w = w0; n = Ee*Ee;  break;
    case 1:  w = w1; n = KVd*Ee; break;
    case 2:  w = w2; n = KVd*Ee; break;
    default: w = w3; n = Ee*KVd; break;
  }
  const int nv = n >> 2;
  double s = 0.0, sa = 0.0;
  for (int i = blockIdx.x * 256 + threadIdx.x; i < nv; i += SB * 256) {
    float4 v = ((const float4*)w)[i];
    s  += (double)v.x + (double)v.y + (double)v.z + (double)v.w;
    sa += (double)fabsf(v.x) + (double)fabsf(v.y) + (double)fabsf(v.z) + (double)fabsf(v.w);
  }
  __shared__ double r0[256], r1[256];
  r0[threadIdx.x] = s; r1[threadIdx.x] = sa;
  __syncthreads();
  for (int st = 128; st > 0; st >>= 1) {
    if (threadIdx.x < st) { r0[threadIdx.x] += r0[threadIdx.x+st]; r1[threadIdx.x] += r1[threadIdx.x+st]; }
    __syncthreads();
  }
  if (threadIdx.x == 0) {
    size_t o = ((size_t)blockIdx.y * SB + blockIdx.x) * 2;
    partials[o]   = r0[0];
    partials[o+1] = r1[0];
  }
}

__global__ __launch_bounds__(64) void weight_stats_fin(
    const double* __restrict__ partials, float* __restrict__ stats)
{
  int m = threadIdx.x;
  if (m < 4) {
    double s = 0.0, sa = 0.0;
    for (int i = 0; i < SB; i++) {
      s  += partials[((size_t)m * SB + i) * 2];
      sa += partials[((size_t)m * SB + i) * 2 + 1];
    }
    int n = (m == 0) ? Ee*Ee : (m == 3 ? Ee*KVd : KVd*Ee);
    stats[2*m]   = (float)(s  / n);
    stats[2*m+1] = (float)(sa / n);
  }
}

// ---------------- ternary weight signs (all 4 matrices, one launch) ----------------
__global__ __launch_bounds__(256) void quant_w_all(
    const float* __restrict__ w0, const float* __restrict__ w1,
    const float* __restrict__ w2, const float* __restrict__ w3,
    int8_t* __restrict__ s0, int8_t* __restrict__ s1,
    int8_t* __restrict__ s2, int8_t* __restrict__ s3,
    const float* __restrict__ stats)
{
  const float* w; int8_t* s; int n; int idx;
  switch (blockIdx.y) {
    case 0:  w = w0; s = s0; n = Ee*Ee;  idx = 0; break;
    case 1:  w = w1; s = s1; n = KVd*Ee; idx = 1; break;
    case 2:  w = w2; s = s2; n = KVd*Ee; idx = 2; break;
    default: w = w3; s = s3; n = Ee*KVd; idx = 3; break;
  }
  int i = blockIdx.x * 256 + threadIdx.x;
  if (i < n) {
    float d = w[i] - stats[2*idx];
    s[i] = (d > 0.f) ? (int8_t)1 : ((d < 0.f) ? (int8_t)-1 : (int8_t)0);
  }
}

// ---------------- fused rmsnorm + int8 act quant (dim=1024, q/k/v in one launch) ----------------
__global__ __launch_bounds__(256) void act_quant_all(
    const float* __restrict__ x0, const float* __restrict__ x1, const float* __restrict__ x2,
    int8_t* __restrict__ q0, int8_t* __restrict__ q1, int8_t* __restrict__ q2,
    float* __restrict__ d0, float* __restrict__ d1, float* __restrict__ d2)
{
  const float* x; int8_t* q; float* dq;
  switch (blockIdx.y) {
    case 0:  x = x0; q = q0; dq = d0; break;
    case 1:  x = x1; q = q1; dq = d1; break;
    default: x = x2; q = q2; dq = d2; break;
  }
  __shared__ float r0[256], r1[256];
  __shared__ float sb[2];
  const int t = blockIdx.x, tid = threadIdx.x;
  float4 a = ((const float4*)(x + (size_t)t * Ee))[tid];
  float ss = a.x*a.x + a.y*a.y + a.z*a.z + a.w*a.w;
  float mx = fmaxf(fmaxf(fabsf(a.x), fabsf(a.y)), fmaxf(fabsf(a.z), fabsf(a.w)));
  r0[tid] = ss; r1[tid] = mx;
  __syncthreads();
  for (int st = 128; st > 0; st >>= 1) {
    if (tid < st) { r0[tid] += r0[tid+st]; r1[tid] = fmaxf(r1[tid], r1[tid+st]); }
    __syncthreads();
  }
  if (tid == 0) {
    float nrm = sqrtf(r0[0]);
    float rn  = sqrtf((float)Ee) / fmaxf(nrm, 1e-12f);
    float sc  = 127.0f / fmaxf(r1[0] * rn, 1e-5f);
    sb[0] = rn; sb[1] = sc;
    dq[t] = 1.0f / sc;
  }
  __syncthreads();
  const float rn = sb[0], sc = sb[1];
  char4 o;
  o.x = (signed char)fmaxf(fminf(rintf((a.x*rn)*sc), 127.f), -128.f);
  o.y = (signed char)fmaxf(fminf(rintf((a.y*rn)*sc), 127.f), -128.f);
  o.z = (signed char)fmaxf(fminf(rintf((a.z*rn)*sc), 127.f), -128.f);
  o.w = (signed char)fmaxf(fminf(rintf((a.w*rn)*sc), 127.f), -128.f);
  ((char4*)(q + (size_t)t * Ee))[tid] = o;
}

// ---------------- int8 x ternary GEMM via MFMA (exact i32 accumulate) ----------------
// 2-phase pipelined: loads for tile k+1 issued AFTER the barrier, BEFORE the
// MFMA cluster of tile k, so global latency hides under MFMAs (T3 minimal).
__device__ __forceinline__ void gemm_core(
    const int8_t* __restrict__ A, const int8_t* __restrict__ Bm,
    const float* __restrict__ xs, const float* __restrict__ stats, int widx,
    float* __restrict__ C, int Nc, int K, int bx, int by)
{
  __shared__ int8_t As[128 * 80];   // 80-B padded rows
  __shared__ int8_t Bs[128 * 80];
  const int tid = threadIdx.x;
  const int row0 = by * 128, col0 = bx * 128;
  const int lane = tid & 63, wave = tid >> 6;
  const int wr = wave >> 1, wc = wave & 1;
  const int c = lane & 15, quad = lane >> 4;

  i32x4 acc[4][4];
  #pragma unroll
  for (int mt = 0; mt < 4; mt++)
    #pragma unroll
    for (int nt = 0; nt < 4; nt++) acc[mt][nt] = (i32x4){0, 0, 0, 0};

  const int srow = tid >> 2;
  const int schunk = (tid & 3) * 16;
  const int8_t* pa0 = A  + (size_t)(row0 + srow)      * K + schunk;
  const int8_t* pa1 = A  + (size_t)(row0 + 64 + srow) * K + schunk;
  const int8_t* pb0 = Bm + (size_t)(col0 + srow)      * K + schunk;
  const int8_t* pb1 = Bm + (size_t)(col0 + 64 + srow) * K + schunk;

  int4 a0 = *(const int4*)(pa0);
  int4 a1 = *(const int4*)(pa1);
  int4 b0 = *(const int4*)(pb0);
  int4 b1 = *(const int4*)(pb1);

  for (int k0 = 0; k0 < K; k0 += 64) {
    __syncthreads();
    *(int4*)&As[srow * 80 + schunk]        = a0;
    *(int4*)&As[(64 + srow) * 80 + schunk] = a1;
    *(int4*)&Bs[srow * 80 + schunk]        = b0;
    *(int4*)&Bs[(64 + srow) * 80 + schunk] = b1;
    __syncthreads();
    // issue next-tile loads before MFMA cluster (latency hidden by MFMAs)
    const int kn = (k0 + 64 < K) ? k0 + 64 : k0;
    a0 = *(const int4*)(pa0 + kn);
    a1 = *(const int4*)(pa1 + kn);
    b0 = *(const int4*)(pb0 + kn);
    b1 = *(const int4*)(pb1 + kn);
    i32x4 af[4], bf[4];
    #pragma unroll
    for (int mt = 0; mt < 4; mt++)
      af[mt] = *(const i32x4*)&As[(wr * 64 + mt * 16 + c) * 80 + quad * 16];
    #pragma unroll
    for (int nt = 0; nt < 4; nt++)
      bf[nt] = *(const i32x4*)&Bs[(wc * 64 + nt * 16 + c) * 80 + quad * 16];
    #pragma unroll
    for (int mt = 0; mt < 4; mt++)
      #pragma unroll
      for (int nt = 0; nt < 4; nt++)
        acc[mt][nt] = __builtin_amdgcn_mfma_i32_16x16x64_i8(af[mt], bf[nt], acc[mt][nt], 0, 0, 0);
  }
  const float wsc = stats[2 * widx + 1];
  #pragma unroll
  for (int mt = 0; mt < 4; mt++)
    #pragma unroll
    for (int j = 0; j < 4; j++) {
      int m = row0 + wr * 64 + mt * 16 + quad * 4 + j;
      float rowscale = xs[m] * wsc;
      #pragma unroll
      for (int nt = 0; nt < 4; nt++)
        C[(size_t)m * Nc + col0 + wc * 64 + nt * 16 + c] = (float)acc[mt][nt][j] * rowscale;
    }
}

__global__ __launch_bounds__(256) void gemm_one(
    const int8_t* __restrict__ A, const int8_t* __restrict__ Bm,
    const float* __restrict__ xs, const float* __restrict__ stats, int widx,
    float* __restrict__ C, int Nc, int K)
{
  gemm_core(A, Bm, xs, stats, widx, C, Nc, K, blockIdx.x, blockIdx.y);
}

__global__ __launch_bounds__(256) void gemm_kv(
    const int8_t* __restrict__ A0, const int8_t* __restrict__ B0,
    const float* __restrict__ xs0, float* __restrict__ C0,
    const int8_t* __restrict__ A1, const int8_t* __restrict__ B1,
    const float* __restrict__ xs1, float* __restrict__ C1,
    const float* __restrict__ stats)
{
  if (blockIdx.z == 0)
    gemm_core(A0, B0, xs0, stats, 1, C0, KVd, Ee, blockIdx.x, blockIdx.y);
  else
    gemm_core(A1, B1, xs1, stats, 2, C1, KVd, Ee, blockIdx.x, blockIdx.y);
}

// ---------------- Pk fp32 [tok][512] -> packed f16 K fragments ----------------
// Layout: [bh][g16 = tok/16][kc=0..3][lane=0..63][8 halves]; chunk = 1 KB.
__global__ __launch_bounds__(256) void k_pack(
    const float* __restrict__ pk, _Float16* __restrict__ kp)
{
  __shared__ __align__(16) _Float16 lt[128][136];
  const int bh = blockIdx.x;      // b*4+h
  const int gq = blockIdx.y;      // 128-token chunk
  const int b = bh >> 2, h = bh & 3;
  const int tid = threadIdx.x;
  const int col = (tid & 31) * 4, r0 = tid >> 5;
  const float* src = pk + ((size_t)(b * Nn + gq * 128)) * KVd + h * HDd;
  #pragma unroll
  for (int p = 0; p < 16; p++) {
    int r = r0 + p * 8;
    float4 v = *(const float4*)(src + (size_t)r * KVd + col);
    lt[r][col+0] = (_Float16)v.x; lt[r][col+1] = (_Float16)v.y;
    lt[r][col+2] = (_Float16)v.z; lt[r][col+3] = (_Float16)v.w;
  }
  __syncthreads();
  const int wave = tid >> 6, lane = tid & 63;
  const int c = lane & 15, quad = lane >> 4;
  #pragma unroll
  for (int q = 0; q < 8; q++) {
    int chunk = wave * 8 + q;       // 0..31
    int gi = chunk >> 2, kc = chunk & 3;
    half8 v = *(const half8*)&lt[gi * 16 + c][kc * 32 + quad * 8];
    *(half8*)(kp + ((((size_t)bh * 128 + gq * 8 + gi) * 4 + kc) << 9) + lane * 8) = v;
  }
}

// ---------------- Pv fp32 [tok][512] -> packed f16 V^T fragments ----------------
// Layout: [bh][st = s/64][chunk = g*2+x, 16 chunks][lane][8 halves]; chunk = 1 KB.
__global__ __launch_bounds__(256) void v_pack(
    const float* __restrict__ pv, _Float16* __restrict__ pvt)
{
  __shared__ __align__(16) _Float16 lt[128][72];
  const int st = blockIdx.x;          // s-tile (64 tokens)
  const int bh = blockIdx.y;          // b*4+h
  const int b = bh >> 2, h = bh & 3;
  const int t = threadIdx.x;
  const int dc = (t & 31) * 4, srow = t >> 5;
  #pragma unroll
  for (int p = 0; p < 8; p++) {
    int s = srow + 8 * p;
    float4 v = *(const float4*)(pv + (size_t)(b * Nn + st * 64 + s) * KVd + h * HDd + dc);
    lt[dc+0][s] = (_Float16)v.x; lt[dc+1][s] = (_Float16)v.y;
    lt[dc+2][s] = (_Float16)v.z; lt[dc+3][s] = (_Float16)v.w;
  }
  __syncthreads();
  const int wave = t >> 6, lane = t & 63;
  const int c = lane & 15, quad = lane >> 4;
  _Float16* ob = pvt + (((size_t)bh * 32 + st) << 13);   // 16 chunks * 512 halves
  #pragma unroll
  for (int q = 0; q < 4; q++) {
    int chunk = wave * 4 + q;      // 0..15 = g*2+x
    int g = chunk >> 1, x = chunk & 1;
    half8 v = *(const half8*)&lt[g * 16 + c][x * 32 + quad * 8];
    *(half8*)(ob + (chunk << 9) + lane * 8) = v;
  }
}

// ---------------- MFMA flash attention (async LDS staging, 2-barrier, hi-occ) ----------------
// Block = 64 q-rows (4 waves x 16), full 32-tile sweep.  K and V each SINGLE
// buffered (16 KB) -> LDS 41 KB -> 3 blocks/CU (12 waves) vs R9's 2.  Two
// barriers/tile: {QK(t) | bar1 | stage K(t+1) | softmax | PV(t) | bar2 |
// stage V(t+1)} -- each async stage lands under >=1 compute phase; each
// barrier's implicit per-wave vmcnt(0) drains the stage issued one phase ago;
// buffer write/read hazards separated by exactly one barrier.
// Softmax offload: l_i computed by ones-vector MFMA (row-sum replicated in
// C-layout) -- deletes red16_sum (VALU) for 2 MFMAs; defer-max THR=8 (exp2
// domain, P<=256 fits f16) skips the O-rescale unless max grows >8.
// Grid (bh=16, qtile=32): wg id % 8 == bh % 8 -> (b,h) pinned to one XCD.
__global__ __launch_bounds__(256, 3) void attn_mfma(
    const float* __restrict__ Pq, const _Float16* __restrict__ Kpk,
    const _Float16* __restrict__ Vpk, float* __restrict__ AO)
{
  __shared__ __align__(16) _Float16 kbuf[8192];      // 16 KB K tile
  __shared__ __align__(16) _Float16 vbuf[8192];      // 16 KB V tile
  __shared__ __align__(16) _Float16 stile[4][1152];  // per-wave P transpose
  const int tid  = threadIdx.x;
  const int wave = tid >> 6;
  const int lane = tid & 63;
  const int c = lane & 15, quad = lane >> 4;
  const int bhid = blockIdx.x;            // b*4 + h
  const int h = bhid & 3, b = bhid >> 2;
  const int qrow0 = (blockIdx.y << 6) + wave * 16;   // 64 rows/block, 16/wave
  const size_t tokbase = (size_t)b * Nn;

  _Float16* st = stile[wave];

  // Q fragments in registers (group-sum, /128 and log2(e) folded -> exp2 domain)
  half8 qa[4];
  {
    const float qsc = 0.0078125f * 1.44269504088896f;
    const float* qp = Pq + (tokbase + qrow0 + c) * Ee + (2 * h) * HDd;
    #pragma unroll
    for (int kc = 0; kc < 4; kc++) {
      int k0 = kc * 32 + quad * 8;
      float4 u0 = *(const float4*)(qp + k0);
      float4 u1 = *(const float4*)(qp + k0 + 4);
      float4 w0 = *(const float4*)(qp + HDd + k0);
      float4 w1 = *(const float4*)(qp + HDd + k0 + 4);
      half8 q8;
      q8[0] = (_Float16)((u0.x + w0.x) * qsc);
      q8[1] = (_Float16)((u0.y + w0.y) * qsc);
      q8[2] = (_Float16)((u0.z + w0.z) * qsc);
      q8[3] = (_Float16)((u0.w + w0.w) * qsc);
      q8[4] = (_Float16)((u1.x + w1.x) * qsc);
      q8[5] = (_Float16)((u1.y + w1.y) * qsc);
      q8[6] = (_Float16)((u1.z + w1.z) * qsc);
      q8[7] = (_Float16)((u1.w + w1.w) * qsc);
      qa[kc] = q8;
    }
  }

  half8 ones;
  #pragma unroll
  for (int e = 0; e < 8; e++) ones[e] = (_Float16)1.0f;

  float4_t oa[8];
  #pragma unroll
  for (int g = 0; g < 8; g++) oa[g] = (float4_t){0.f, 0.f, 0.f, 0.f};
  float m_i[4] = {-1e30f, -1e30f, -1e30f, -1e30f};
  float l_i[4] = {0.f, 0.f, 0.f, 0.f};

  const _Float16* kpkBH = Kpk + ((size_t)bhid << 18);
  const _Float16* vpkBH = Vpk + ((size_t)bhid << 18);

  // this wave's 4 staging chunks of each of K and V
  const int ci0 = wave * 4;

  // ---- prologue: stage tile 0 (K and V) ----
  #pragma unroll
  for (int q = 0; q < 4; q++) {
    const int ci = ci0 + q;
    gload_lds16(kpkBH + ((size_t)ci << 9) + lane * 8, &kbuf[(size_t)ci << 9]);
    gload_lds16(vpkBH + ((size_t)ci << 9) + lane * 8, &vbuf[(size_t)ci << 9]);
  }
  __syncthreads();   // implicit vmcnt(0): tile 0 resident

  for (int kt = 0; kt < 32; kt++) {
    // ---- S = Q K^T from LDS K ----
    float4_t sfr[4];
    #pragma unroll
    for (int nb = 0; nb < 4; nb++) {
      float4_t acc = (float4_t){0.f, 0.f, 0.f, 0.f};
      #pragma unroll
      for (int kc = 0; kc < 4; kc++) {
        half8 kf = *(const half8*)&kbuf[(((nb << 2) + kc) << 9) + lane * 8];
        acc = __builtin_amdgcn_mfma_f32_16x16x32_f16(qa[kc], kf, acc, 0, 0, 0);
      }
      sfr[nb] = acc;
    }
    __syncthreads();   // barrier 1: all waves done reading kbuf; V(kt) drained
    // ---- stage K(kt+1) (async; lands under softmax+PV) ----
    if (kt < 31) {
      const size_t tb = (size_t)(kt + 1) << 13;
      #pragma unroll
      for (int q = 0; q < 4; q++) {
        const int ci = ci0 + q;
        gload_lds16(kpkBH + tb + ((size_t)ci << 9) + lane * 8, &kbuf[(size_t)ci << 9]);
      }
    }
    // ---- online softmax (exp2 domain), defer-max THR=8 ----
    float tmax[4];
    bool big = false;
    #pragma unroll
    for (int j = 0; j < 4; j++) {
      float t = fmaxf(fmaxf(sfr[0][j], sfr[1][j]), fmaxf(sfr[2][j], sfr[3][j]));
      t = red16_max(t);
      tmax[j] = t;
      big = big || (t > m_i[j] + 8.0f);
    }
    if (__any(big)) {
      float alpha[4];
      #pragma unroll
      for (int j = 0; j < 4; j++) {
        float mnew = fmaxf(m_i[j], tmax[j]);
        alpha[j] = exp2f(m_i[j] - mnew);
        m_i[j] = mnew;
        l_i[j] *= alpha[j];
      }
      #pragma unroll
      for (int g = 0; g < 8; g++) {
        oa[g][0] *= alpha[0]; oa[g][1] *= alpha[1];
        oa[g][2] *= alpha[2]; oa[g][3] *= alpha[3];
      }
    }
    #pragma unroll
    for (int nb = 0; nb < 4; nb++)
      #pragma unroll
      for (int j = 0; j < 4; j++)
        sfr[nb][j] = exp2f(sfr[nb][j] - m_i[j]);   // bounded by 2^8
    // ---- P: C-layout -> wave-private LDS -> A-layout ----
    #pragma unroll
    for (int nb = 0; nb < 4; nb++)
      #pragma unroll
      for (int j = 0; j < 4; j++)
        st[(quad * 4 + j) * 72 + nb * 16 + c] = (_Float16)sfr[nb][j];
    half8 pa0 = *(const half8*)&st[c * 72 + quad * 8];
    half8 pa1 = *(const half8*)&st[c * 72 + 32 + quad * 8];
    // ---- l via ones-MFMA (row-sum of f16 P, replicated over cols) ----
    float4_t accl = (float4_t){0.f, 0.f, 0.f, 0.f};
    accl = __builtin_amdgcn_mfma_f32_16x16x32_f16(pa0, ones, accl, 0, 0, 0);
    accl = __builtin_amdgcn_mfma_f32_16x16x32_f16(pa1, ones, accl, 0, 0, 0);
    #pragma unroll
    for (int j = 0; j < 4; j++) l_i[j] += accl[j];
    // ---- PV from LDS V ----
    #pragma unroll
    for (int g = 0; g < 8; g++) {
      half8 v0 = *(const half8*)&vbuf[(((g << 1) + 0) << 9) + lane * 8];
      half8 v1 = *(const half8*)&vbuf[(((g << 1) + 1) << 9) + lane * 8];
      oa[g] = __builtin_amdgcn_mfma_f32_16x16x32_f16(pa0, v0, oa[g], 0, 0, 0);
      oa[g] = __builtin_amdgcn_mfma_f32_16x16x32_f16(pa1, v1, oa[g], 0, 0, 0);
    }
    __syncthreads();   // barrier 2: all waves done reading vbuf; K(kt+1) drained
    // ---- stage V(kt+1) (async; lands under next tile's QK) ----
    if (kt < 31) {
      const size_t tb = (size_t)(kt + 1) << 13;
      #pragma unroll
      for (int q = 0; q < 4; q++) {
        const int ci = ci0 + q;
        gload_lds16(vpkBH + tb + ((size_t)ci << 9) + lane * 8, &vbuf[(size_t)ci << 9]);
      }
    }
  }

  // ---- epilogue: each wave writes its own 16 rows (no merge) ----
  float invl[4];
  #pragma unroll
  for (int j = 0; j < 4; j++) invl[j] = 1.0f / l_i[j];
  #pragma unroll
  for (int g = 0; g < 8; g++)
    #pragma unroll
    for (int j = 0; j < 4; j++)
      AO[(tokbase + qrow0 + quad * 4 + j) * KVd + h * HDd + g * 16 + c] = oa[g][j] * invl[j];
}

// ---------------- fused LayerNorm + rmsnorm + int8 quant (dim=512) ----------------
__global__ __launch_bounds__(128) void ln_quant(
    const float* __restrict__ AO, const float* __restrict__ g, const float* __restrict__ be,
    int8_t* __restrict__ oq, float* __restrict__ dq)
{
  __shared__ float r0[128], r1[128];
  __shared__ float sb[2];
  const int t = blockIdx.x, tid = threadIdx.x;
  float4 a = ((const float4*)(AO + (size_t)t * KVd))[tid];
  float s  = a.x + a.y + a.z + a.w;
  float ss = a.x*a.x + a.y*a.y + a.z*a.z + a.w*a.w;
  r0[tid] = s; r1[tid] = ss;
  __syncthreads();
  for (int st = 64; st > 0; st >>= 1) {
    if (tid < st) { r0[tid] += r0[tid+st]; r1[tid] += r1[tid+st]; }
    __syncthreads();
  }
  if (tid == 0) {
    float mu  = r0[0] / (float)KVd;
    float var = r1[0] / (float)KVd - mu*mu;
    sb[0] = mu;
    sb[1] = 1.0f / sqrtf(var + 1e-5f);
  }
  __syncthreads();
  const float mu = sb[0], iv = sb[1];
  float4 gv = ((const float4*)g)[tid];
  float4 bv = ((const float4*)be)[tid];
  float4 y;
  y.x = (a.x - mu) * iv * gv.x + bv.x;
  y.y = (a.y - mu) * iv * gv.y + bv.y;
  y.z = (a.z - mu) * iv * gv.z + bv.z;
  y.w = (a.w - mu) * iv * gv.w + bv.w;
  float ss2 = y.x*y.x + y.y*y.y + y.z*y.z + y.w*y.w;
  float mx  = fmaxf(fmaxf(fabsf(y.x), fabsf(y.y)), fmaxf(fabsf(y.z), fabsf(y.w)));
  __syncthreads();
  r0[tid] = ss2; r1[tid] = mx;
  __syncthreads();
  for (int st = 64; st > 0; st >>= 1) {
    if (tid < st) { r0[tid] += r0[tid+st]; r1[tid] = fmaxf(r1[tid], r1[tid+st]); }
    __syncthreads();
  }
  if (tid == 0) {
    float nrm = sqrtf(r0[0]);
    float rn  = sqrtf((float)KVd) / fmaxf(nrm, 1e-12f);
    float sc  = 127.0f / fmaxf(r1[0] * rn, 1e-5f);
    sb[0] = rn; sb[1] = sc;
    dq[t] = 1.0f / sc;
  }
  __syncthreads();
  const float rn = sb[0], sc = sb[1];
  char4 o;
  o.x = (signed char)fmaxf(fminf(rintf((y.x*rn)*sc), 127.f), -128.f);
  o.y = (signed char)fmaxf(fminf(rintf((y.y*rn)*sc), 127.f), -128.f);
  o.z = (signed char)fmaxf(fminf(rintf((y.z*rn)*sc), 127.f), -128.f);
  o.w = (signed char)fmaxf(fminf(rintf((y.w*rn)*sc), 127.f), -128.f);
  ((char4*)(oq + (size_t)t * KVd))[tid] = o;
}

// ---------------- launch ----------------
extern "C" void kernel_launch(void* const* d_in, const int* in_sizes, int n_in,
                              void* d_out, int out_size, void* d_ws, size_t ws_size,
                              hipStream_t stream)
{
  (void)in_sizes; (void)n_in; (void)out_size; (void)ws_size;
  const float* query = (const float*)d_in[0];
  const float* key_  = (const float*)d_in[1];
  const float* value = (const float*)d_in[2];
  const float* w_q   = (const float*)d_in[3];
  const float* w_k   = (const float*)d_in[4];
  const float* w_v   = (const float*)d_in[5];
  const float* w_o   = (const float*)d_in[6];
  const float* ln_g  = (const float*)d_in[7];
  const float* ln_b  = (const float*)d_in[8];
  float* out = (float*)d_out;

  char* ws = (char*)d_ws;
  float*     stats = (float*)    (ws + OFF_STATS);
  int8_t*    s_q   = (int8_t*)   (ws + OFF_SQ);
  int8_t*    s_k   = (int8_t*)   (ws + OFF_SK);
  int8_t*    s_v   = (int8_t*)   (ws + OFF_SV);
  int8_t*    s_o   = (int8_t*)   (ws + OFF_SO);
  int8_t*    xq_q  = (int8_t*)   (ws + OFF_XQQ);
  int8_t*    xq_k  = (int8_t*)   (ws + OFF_XQK);
  int8_t*    xq_v  = (int8_t*)   (ws + OFF_XQV);
  float*     xs_q  = (float*)    (ws + OFF_XSQ);
  float*     xs_k  = (float*)    (ws + OFF_XSK);
  float*     xs_v  = (float*)    (ws + OFF_XSV);
  float*     Pq    = (float*)    (ws + OFF_PQ);
  float*     Pk    = (float*)    (ws + OFF_PK);
  float*     Pv    = (float*)    (ws + OFF_PV);
  double*    part  = (double*)   (ws + OFF_PART);
  _Float16*  Kpk   = (_Float16*) (ws + OFF_PKH);
  _Float16*  Vpk   = (_Float16*) (ws + OFF_PVT);
  float*     AO    = (float*)    (ws + OFF_AO);
  int8_t*    oq    = (int8_t*)   (ws + OFF_OQ);
  float*     os_   = (float*)    (ws + OFF_OS);

  weight_stats_part<<<dim3(SB, 4), dim3(256), 0, stream>>>(w_q, w_k, w_v, w_o, part);
  weight_stats_fin<<<dim3(1), dim3(64), 0, stream>>>(part, stats);

  quant_w_all<<<dim3((Ee*Ee)/256, 4), dim3(256), 0, stream>>>(
      w_q, w_k, w_v, w_o, s_q, s_k, s_v, s_o, stats);

  act_quant_all<<<dim3(Tt, 3), dim3(256), 0, stream>>>(
      query, key_, value, xq_q, xq_k, xq_v, xs_q, xs_k, xs_v);

  gemm_one<<<dim3(Ee/128, Tt/128), dim3(256), 0, stream>>>(xq_q, s_q, xs_q, stats, 0, Pq, Ee, Ee);
  gemm_kv<<<dim3(KVd/128, Tt/128, 2), dim3(256), 0, stream>>>(
      xq_k, s_k, xs_k, Pk, xq_v, s_v, xs_v, Pv, stats);

  k_pack<<<dim3(Bb*KVH, Nn/128), dim3(256), 0, stream>>>(Pk, Kpk);
  v_pack<<<dim3(Nn/64, Bb*KVH), dim3(256), 0, stream>>>(Pv, Vpk);

  // grid x = bh so wg-id % 8 == bh % 8 -> (b,h) pinned to one XCD (K/V L2-resident)
  attn_mfma<<<dim3(Bb*KVH, Nn/64), dim3(256), 0, stream>>>(Pq, Kpk, Vpk, AO);

  ln_quant<<<dim3(Tt), dim3(128), 0, stream>>>(AO, ln_g, ln_b, oq, os_);

  gemm_one<<<dim3(Ee/128, Tt/128), dim3(256), 0, stream>>>(oq, s_o, os_, stats, 3, out, Ee, KVd);
}